// Round 13
// baseline (416.114 us; speedup 1.0000x reference)
//
#include <hip/hip_runtime.h>

// Problem constants
static constexpr int L_ = 3, B_ = 8, C_ = 64, N_ = 1024;
static constexpr int PLANE = C_ * N_;       // 65536
static constexpr int SZ    = L_ * B_ * PLANE; // 1572864
static constexpr int BPL   = B_ * PLANE;    // 524288

#define DI __device__ __forceinline__

typedef _Float16 h8 __attribute__((ext_vector_type(8)));   // 8 fp16 (MFMA A/B frag)
typedef __attribute__((ext_vector_type(4))) float f32x4;   // MFMA C/D frag
typedef unsigned int uint32;

DI float wred_sum(float v) {
#pragma unroll
  for (int m = 1; m < 64; m <<= 1) v += __shfl_xor(v, m, 64);
  return v;
}

DI unsigned short f2h(float f) {
  return __builtin_bit_cast(unsigned short, (_Float16)f);
}
DI uint32 pkh(float a, float b) {
  return (uint32)f2h(a) | ((uint32)f2h(b) << 16);
}
DI h8 bch8(uint4 v) { return __builtin_bit_cast(h8, v); }

DI f32x4 mfmah(h8 a, h8 b, f32x4 c) {
  return __builtin_amdgcn_mfma_f32_16x16x32_f16(a, b, c, 0, 0, 0);
}

// ---------------------------------------------------------------------------
// xprep: transpose+convert in[g][K][N] fp32 -> out[g][N][K] fp16.
// grid (8, K/64, N/64); 64x64 tile per block.
// ---------------------------------------------------------------------------
__global__ __launch_bounds__(256) void xprep_kernel(
    const float* __restrict__ in, unsigned short* __restrict__ out, int K, int N)
{
  const int g = blockIdx.x, kc = blockIdx.y, nc = blockIdx.z;
  const int t = threadIdx.x;
  __shared__ float tl[64][65];
  const float* ing = in + (size_t)g * K * N + (size_t)(kc * 64) * N + nc * 64;
#pragma unroll 4
  for (int r = 0; r < 16; ++r) {
    const int kk = r * 4 + (t >> 6);
    tl[kk][t & 63] = ing[(size_t)kk * N + (t & 63)];
  }
  __syncthreads();
  const int mm = t >> 2, kseg = (t & 3) * 16;
  uint32 hw[8];
#pragma unroll
  for (int ii = 0; ii < 8; ++ii)
    hw[ii] = pkh(tl[kseg + 2 * ii][mm], tl[kseg + 2 * ii + 1][mm]);
  unsigned short* o = out + ((size_t)g * N + nc * 64 + mm) * K + kc * 64 + kseg;
  uint4 h0; h0.x = hw[0]; h0.y = hw[1]; h0.z = hw[2]; h0.w = hw[3];
  uint4 h1; h1.x = hw[4]; h1.y = hw[5]; h1.z = hw[6]; h1.w = hw[7];
  *reinterpret_cast<uint4*>(o)     = h0;
  *reinterpret_cast<uint4*>(o + 8) = h1;
}

// ---------------------------------------------------------------------------
// w9conv: conv weights w[co][ci][k9] fp32 -> w9[k9][co][ci] fp16 (both s,t).
// grid 576.
// ---------------------------------------------------------------------------
__global__ __launch_bounds__(256) void w9conv_kernel(
    const float* __restrict__ w_s, const float* __restrict__ w_t,
    unsigned short* __restrict__ w9_s, unsigned short* __restrict__ w9_t)
{
  const int e = blockIdx.x * 256 + threadIdx.x;  // 0..147455
  const float* w = (e < 73728) ? w_s : w_t;
  unsigned short* o = (e < 73728) ? w9_s : w9_t;
  const int le = (e < 73728) ? e : e - 73728;
  const int ci = le & 127;
  const int q = le >> 7;
  const int co = q & 63;
  const int k9 = q >> 6;
  o[le] = f2h(w[(co * 128 + ci) * 9 + k9]);
}

// ---------------------------------------------------------------------------
// conv0 via MFMA: 3x3 s2 p1, 128->64, using channels-last fp16 inT[b][pix][ci]
// and w9[tap][co][ci]. grid (32 out-rows, 8 b, 2 st), 256 thr = 4 waves.
// ---------------------------------------------------------------------------
__global__ __launch_bounds__(256) void conv0_mfma_kernel(
    const unsigned short* __restrict__ inT_s, const unsigned short* __restrict__ inT_t,
    const unsigned short* __restrict__ w9_s, const unsigned short* __restrict__ w9_t,
    const float* __restrict__ b_s, const float* __restrict__ b_t,
    float* __restrict__ Sout, float* __restrict__ Tout, float* __restrict__ tdup)
{
  const int yr = blockIdx.x;          // output row 0..31
  const int b  = blockIdx.y;
  const int st = blockIdx.z;
  const unsigned short* inT = st ? inT_t : inT_s;
  const unsigned short* w9  = st ? w9_t  : w9_s;
  const float* bias = st ? b_t : b_s;
  float* outA = st ? Tout : Sout;

  const int t = threadIdx.x, lane = t & 63;
  const int ct = t >> 6;              // co-tile
  const int nl = lane & 15, g16 = lane >> 4;
  const unsigned short* inb = inT + (size_t)b * (4096 * 128);
  const unsigned short* wbase = w9 + (size_t)(ct * 16 + nl) * 128;

  f32x4 acc0 = f32x4{0.f, 0.f, 0.f, 0.f};
  f32x4 acc1 = f32x4{0.f, 0.f, 0.f, 0.f};
  const uint4 zz = uint4{0u, 0u, 0u, 0u};

#pragma unroll 1
  for (int tap = 0; tap < 9; ++tap) {
    const int ky = tap / 3, kx = tap - 3 * (tap / 3);
    const int py = 2 * yr - 1 + ky;                 // [-1, 63]
    const int px0 = 2 * nl - 1 + kx;                // nt=0: x = nl
    const int px1 = px0 + 32;                       // nt=1: x = 16+nl (>=31)
    const bool v0 = (py >= 0) && (px0 >= 0);
    const bool v1 = (py >= 0);
    const unsigned short* prow = inb + (ptrdiff_t)py * (64 * 128);
#pragma unroll
    for (int ks = 0; ks < 4; ++ks) {
      const h8 a = bch8(*reinterpret_cast<const uint4*>(
          wbase + tap * 8192 + ks * 32 + g16 * 8));
      const uint4 bv0 = v0 ? *reinterpret_cast<const uint4*>(
                                 prow + px0 * 128 + ks * 32 + g16 * 8) : zz;
      const uint4 bv1 = v1 ? *reinterpret_cast<const uint4*>(
                                 prow + px1 * 128 + ks * 32 + g16 * 8) : zz;
      acc0 = mfmah(a, bch8(bv0), acc0);
      acc1 = mfmah(a, bch8(bv1), acc1);
    }
  }

  const int yb = yr * 32;
#pragma unroll
  for (int r = 0; r < 4; ++r) {
    const int co = ct * 16 + g16 * 4 + r;
    const float bv = bias[co];
    const int idx = (b * 64 + co) * 1024 + yb + nl;
    const float o0 = acc0[r] + bv;
    const float o1 = acc1[r] + bv;
    outA[idx] = o0; outA[idx + 16] = o1;
    if (st) { tdup[idx] = o0; tdup[idx + 16] = o1; }
  }
}

// ---------------------------------------------------------------------------
// Generic fp32 out[g][64][1024] = W[g/wdiv][64][K] @ X[g][K][1024] + bias
// (kept for attn_cam @ vc)
// ---------------------------------------------------------------------------
__global__ __launch_bounds__(256) void gemm64_kernel(
    const float* __restrict__ W, int wstride, int wdiv,
    const float* __restrict__ X, int xstride,
    float* __restrict__ out, int ostride,
    const float* __restrict__ bias, int bstride,
    int K)
{
  const int g  = blockIdx.x;
  const int n0 = blockIdx.y * 64;
  const float* Wg = W + (size_t)(g / wdiv) * wstride;
  const float* Xg = X + (size_t)g * xstride;
  const int t = threadIdx.x;
  __shared__ float Xs[32][64];
  __shared__ float Ws[32][64];
  const int tn = t & 15, cgp = t >> 4;
  const int n4 = tn * 4, co4 = cgp * 4;
  float acc[4][4] = {};

  for (int k0 = 0; k0 < K; k0 += 32) {
    {
      const int kk = t >> 4;
      const int nn = (t & 15) * 4;
      *reinterpret_cast<float4*>(&Xs[kk][nn]) =
          *reinterpret_cast<const float4*>(Xg + (size_t)(k0 + kk) * N_ + n0 + nn);
      *reinterpret_cast<float4*>(&Xs[kk + 16][nn]) =
          *reinterpret_cast<const float4*>(Xg + (size_t)(k0 + kk + 16) * N_ + n0 + nn);
    }
    {
      const int co = t & 63, q4 = t >> 6;
      const float* wp = Wg + (size_t)co * K + k0 + q4 * 8;
      const float4 a = *reinterpret_cast<const float4*>(wp);
      const float4 c = *reinterpret_cast<const float4*>(wp + 4);
      const int kb = q4 * 8;
      Ws[kb + 0][co] = a.x; Ws[kb + 1][co] = a.y; Ws[kb + 2][co] = a.z; Ws[kb + 3][co] = a.w;
      Ws[kb + 4][co] = c.x; Ws[kb + 5][co] = c.y; Ws[kb + 6][co] = c.z; Ws[kb + 7][co] = c.w;
    }
    __syncthreads();
#pragma unroll
    for (int kk = 0; kk < 32; ++kk) {
      const float4 xv = *reinterpret_cast<const float4*>(&Xs[kk][n4]);
      const float4 wv = *reinterpret_cast<const float4*>(&Ws[kk][co4]);
      const float xa[4] = {xv.x, xv.y, xv.z, xv.w};
      const float wa[4] = {wv.x, wv.y, wv.z, wv.w};
#pragma unroll
      for (int a = 0; a < 4; ++a)
#pragma unroll
        for (int b2 = 0; b2 < 4; ++b2)
          acc[a][b2] = fmaf(wa[a], xa[b2], acc[a][b2]);
    }
    __syncthreads();
  }

  float bv[4] = {0.f, 0.f, 0.f, 0.f};
  if (bias) {
    const float* bg = bias + (size_t)(g / wdiv) * bstride;
    bv[0] = bg[co4]; bv[1] = bg[co4 + 1]; bv[2] = bg[co4 + 2]; bv[3] = bg[co4 + 3];
  }
#pragma unroll
  for (int ii = 0; ii < 4; ++ii) {
    float4 o4;
    o4.x = acc[ii][0] + bv[ii]; o4.y = acc[ii][1] + bv[ii];
    o4.z = acc[ii][2] + bv[ii]; o4.w = acc[ii][3] + bv[ii];
    *reinterpret_cast<float4*>(out + (size_t)g * ostride + (co4 + ii) * N_ + n0 + n4) = o4;
  }
}

// ---------------------------------------------------------------------------
// proj: all 4 projections (q,k,v,vc) in ONE launch. grid (24, 16, 4).
// ---------------------------------------------------------------------------
__global__ __launch_bounds__(256) void proj_kernel(
    const float* __restrict__ Tm, const float* __restrict__ Sm,
    const float* __restrict__ wq, const float* __restrict__ wk,
    const float* __restrict__ wv2, const float* __restrict__ wc,
    const float* __restrict__ bq, const float* __restrict__ bk,
    const float* __restrict__ bv2, const float* __restrict__ bc,
    float* __restrict__ outbase)
{
  const int g  = blockIdx.x;          // i*8+b
  const int n0 = blockIdx.y * 64;
  const int z  = blockIdx.z;          // 0=q 1=k 2=v 3=vc
  const float* W  = (z == 0) ? wq : (z == 1) ? wk : (z == 2) ? wv2 : wc;
  const float* bi = (z == 0) ? bq : (z == 1) ? bk : (z == 2) ? bv2 : bc;
  const float* Xg = ((z == 1) ? Sm : Tm) + (size_t)g * PLANE;
  float* out = outbase + (size_t)z * SZ + (size_t)g * PLANE;
  const float* Wg = W + (g >> 3) * 4096;
  const float* bg = bi + (g >> 3) * 64;

  const int t = threadIdx.x;
  __shared__ float Xs[32][64];
  __shared__ float Ws[32][64];
  const int tn = t & 15, cgp = t >> 4;
  const int n4 = tn * 4, co4 = cgp * 4;
  float acc[4][4] = {};

#pragma unroll 1
  for (int k0 = 0; k0 < 64; k0 += 32) {
    {
      const int kk = t >> 4;
      const int nn = (t & 15) * 4;
      *reinterpret_cast<float4*>(&Xs[kk][nn]) =
          *reinterpret_cast<const float4*>(Xg + (size_t)(k0 + kk) * N_ + n0 + nn);
      *reinterpret_cast<float4*>(&Xs[kk + 16][nn]) =
          *reinterpret_cast<const float4*>(Xg + (size_t)(k0 + kk + 16) * N_ + n0 + nn);
    }
    {
      const int co = t & 63, q4 = t >> 6;
      const float* wp = Wg + (size_t)co * 64 + k0 + q4 * 8;
      const float4 a = *reinterpret_cast<const float4*>(wp);
      const float4 c = *reinterpret_cast<const float4*>(wp + 4);
      const int kb = q4 * 8;
      Ws[kb + 0][co] = a.x; Ws[kb + 1][co] = a.y; Ws[kb + 2][co] = a.z; Ws[kb + 3][co] = a.w;
      Ws[kb + 4][co] = c.x; Ws[kb + 5][co] = c.y; Ws[kb + 6][co] = c.z; Ws[kb + 7][co] = c.w;
    }
    __syncthreads();
#pragma unroll
    for (int kk = 0; kk < 32; ++kk) {
      const float4 xv = *reinterpret_cast<const float4*>(&Xs[kk][n4]);
      const float4 wv = *reinterpret_cast<const float4*>(&Ws[kk][co4]);
      const float xa[4] = {xv.x, xv.y, xv.z, xv.w};
      const float wa[4] = {wv.x, wv.y, wv.z, wv.w};
#pragma unroll
      for (int a = 0; a < 4; ++a)
#pragma unroll
        for (int b2 = 0; b2 < 4; ++b2)
          acc[a][b2] = fmaf(wa[a], xa[b2], acc[a][b2]);
    }
    __syncthreads();
  }

#pragma unroll
  for (int ii = 0; ii < 4; ++ii) {
    const float bv = bg[co4 + ii];
    float4 o4;
    o4.x = acc[ii][0] + bv; o4.y = acc[ii][1] + bv;
    o4.z = acc[ii][2] + bv; o4.w = acc[ii][3] + bv;
    *reinterpret_cast<float4*>(out + (co4 + ii) * N_ + n0 + n4) = o4;
  }
}

// ---------------------------------------------------------------------------
// whconv: fit-GEMM weights to fp16: wh1s@0, wh2s@16384, wh1t@49152, wh2t@65536
// ---------------------------------------------------------------------------
__global__ __launch_bounds__(256) void whconv_kernel(
    const float* __restrict__ w1s, const float* __restrict__ w2s,
    const float* __restrict__ w1t, const float* __restrict__ w2t,
    unsigned short* __restrict__ wh)
{
  const int p = blockIdx.x * 256 + threadIdx.x;  // pair index 0..49151
  const float* in; int local; unsigned short* out;
  if (p < 8192)       { in = w1s; local = p;         out = wh; }
  else if (p < 24576) { in = w2s; local = p - 8192;  out = wh + 16384; }
  else if (p < 32768) { in = w1t; local = p - 24576; out = wh + 49152; }
  else                { in = w2t; local = p - 32768; out = wh + 65536; }
  const float2 v = *reinterpret_cast<const float2*>(in + 2 * local);
  *reinterpret_cast<uint32*>(out + 2 * local) = pkh(v.x, v.y);
}

// ---------------------------------------------------------------------------
// gemmh: fp16 MFMA fit-GEMM. out[g][64co][1024n] = W[64][K] @ Xh[n][K].
// grid (16, 16); g<8 = src, g>=8 = tgt (+dual write).
// ---------------------------------------------------------------------------
__global__ __launch_bounds__(256) void gemmh_kernel(
    const unsigned short* __restrict__ Xa, const unsigned short* __restrict__ Xb,
    const unsigned short* __restrict__ Wa, const unsigned short* __restrict__ Wb,
    const float* __restrict__ ba, const float* __restrict__ bb,
    float* __restrict__ oa, float* __restrict__ ob, float* __restrict__ o2b,
    int K)
{
  const int g = blockIdx.x;
  const bool isb = g >= 8;
  const int gl = g & 7;
  const unsigned short* X = (isb ? Xb : Xa) + (size_t)gl * 1024 * K;
  const unsigned short* W = isb ? Wb : Wa;
  const float* bias = isb ? bb : ba;
  float* out = (isb ? ob : oa) + (size_t)gl * PLANE;
  float* out2 = isb ? o2b + (size_t)gl * PLANE : nullptr;

  const int t = threadIdx.x, lane = t & 63, wv = t >> 6;
  const int nl = lane & 15, g16 = lane >> 4;
  const int n0w = blockIdx.y * 64 + wv * 16;

  const unsigned short* xp = X + (size_t)(n0w + nl) * K + g16 * 8;
  const unsigned short* wp = W + (size_t)nl * K + g16 * 8;

  f32x4 acc[4];
#pragma unroll
  for (int ct = 0; ct < 4; ++ct) acc[ct] = f32x4{0.f, 0.f, 0.f, 0.f};

#pragma unroll 4
  for (int kk = 0; kk < K; kk += 32) {
    const h8 a = bch8(*reinterpret_cast<const uint4*>(xp + kk));
#pragma unroll
    for (int ct = 0; ct < 4; ++ct) {
      const h8 bfr = bch8(*reinterpret_cast<const uint4*>(wp + (size_t)ct * 16 * K + kk));
      acc[ct] = mfmah(a, bfr, acc[ct]);
    }
  }

#pragma unroll
  for (int ct = 0; ct < 4; ++ct) {
    const int co = ct * 16 + nl;
    const float bv = bias[co];
    float4 o4;
    o4.x = acc[ct][0] + bv; o4.y = acc[ct][1] + bv;
    o4.z = acc[ct][2] + bv; o4.w = acc[ct][3] + bv;
    const int idx = co * N_ + n0w + g16 * 4;
    *reinterpret_cast<float4*>(out + idx) = o4;
    if (out2) {
      out2[idx] = o4.x; out2[idx + 1] = o4.y;
      out2[idx + 2] = o4.z; out2[idx + 3] = o4.w;
    }
  }
}

// ---------------------------------------------------------------------------
// kprep: k[g][64c][1024m] -> kT[g][1024m][64c] (fp16); v[g] -> vh[g] (fp16).
// grid (24, 4)
// ---------------------------------------------------------------------------
__global__ __launch_bounds__(256) void kprep_kernel(
    const float* __restrict__ kb, const float* __restrict__ vb,
    unsigned short* __restrict__ kT, unsigned short* __restrict__ vh)
{
  const int g = blockIdx.x;
  const int ch = blockIdx.y;
  const int t = threadIdx.x;
  const float* kg = kb + (size_t)g * PLANE;
  __shared__ float tl[64][65];

#pragma unroll 1
  for (int tile = 0; tile < 4; ++tile) {
    const int m0 = ch * 256 + tile * 64;
    __syncthreads();
#pragma unroll 4
    for (int r = 0; r < 16; ++r) {
      const int c = r * 4 + (t >> 6);
      tl[c][t & 63] = kg[c * N_ + m0 + (t & 63)];
    }
    __syncthreads();
    const int mm = t >> 2, cseg = (t & 3) * 16;
    uint32 hw[8];
#pragma unroll
    for (int ii = 0; ii < 8; ++ii)
      hw[ii] = pkh(tl[cseg + 2 * ii][mm], tl[cseg + 2 * ii + 1][mm]);
    const size_t o = ((size_t)g * 1024 + m0 + mm) * 64 + cseg;
    uint4 h0; h0.x = hw[0]; h0.y = hw[1]; h0.z = hw[2]; h0.w = hw[3];
    uint4 h1; h1.x = hw[4]; h1.y = hw[5]; h1.z = hw[6]; h1.w = hw[7];
    *reinterpret_cast<uint4*>(kT + o)     = h0;
    *reinterpret_cast<uint4*>(kT + o + 8) = h1;
  }

  const float* vg = vb + (size_t)g * PLANE;
  unsigned short* vo = vh + (size_t)g * PLANE;
  for (int e8 = ch * 2048 + t; e8 < (ch + 1) * 2048; e8 += 256) {
    const float4 a = *reinterpret_cast<const float4*>(vg + (size_t)e8 * 8);
    const float4 b = *reinterpret_cast<const float4*>(vg + (size_t)e8 * 8 + 4);
    uint4 u;
    u.x = pkh(a.x, a.y); u.y = pkh(a.z, a.w);
    u.z = pkh(b.x, b.y); u.w = pkh(b.z, b.w);
    *reinterpret_cast<uint4*>(vo + (size_t)e8 * 8) = u;
  }
}

// ---------------------------------------------------------------------------
// e_cam[i,j,b][c][d] = sum_n T[i,b,c,n] * S[j,b,d,n];  also atomic raw-sum.
// ---------------------------------------------------------------------------
__global__ __launch_bounds__(256) void ecam_kernel(
    const float* __restrict__ T, const float* __restrict__ S,
    float* __restrict__ ecam, float* __restrict__ esum_cam)
{
  const int bx = blockIdx.x;
  const int b = bx & 7;
  const int j = (bx >> 3) % 3;
  const int i = bx / 24;
  const float* Tg = T + (size_t)(i * 8 + b) * PLANE;
  const float* Sg = S + (size_t)(j * 8 + b) * PLANE;
  const int t = threadIdx.x;
  __shared__ float Ts[64 * 68];
  __shared__ float Ss[64 * 68];
  __shared__ float rs[4];
  float acc[4][4] = {};
  const int c0 = (t & 15) * 4, d0 = (t >> 4) * 4;

  for (int nb = 0; nb < 1024; nb += 64) {
    __syncthreads();
    {
      const int nn = t & 63, rb = t >> 6;
#pragma unroll
      for (int r = 0; r < 16; ++r) {
        const int row = rb * 16 + r;
        Ts[nn * 68 + row] = Tg[row * N_ + nb + nn];
        Ss[nn * 68 + row] = Sg[row * N_ + nb + nn];
      }
    }
    __syncthreads();
#pragma unroll 8
    for (int nn = 0; nn < 64; ++nn) {
      const float4 tv = *reinterpret_cast<const float4*>(&Ts[nn * 68 + c0]);
      const float4 sv = *reinterpret_cast<const float4*>(&Ss[nn * 68 + d0]);
      const float ta[4] = {tv.x, tv.y, tv.z, tv.w};
      const float sa[4] = {sv.x, sv.y, sv.z, sv.w};
#pragma unroll
      for (int ci = 0; ci < 4; ++ci)
#pragma unroll
        for (int di = 0; di < 4; ++di)
          acc[ci][di] = fmaf(ta[ci], sa[di], acc[ci][di]);
    }
  }
  float s = 0.f;
#pragma unroll
  for (int ci = 0; ci < 4; ++ci)
#pragma unroll
    for (int di = 0; di < 4; ++di) s += acc[ci][di];
  s = wred_sum(s);
  if ((t & 63) == 0) rs[t >> 6] = s;
  __syncthreads();
  if (t == 0) atomicAdd(esum_cam + i * 3 + j, rs[0] + rs[1] + rs[2] + rs[3]);

  float* eo = ecam + (size_t)((i * 3 + j) * 8 + b) * 4096;
#pragma unroll
  for (int ci = 0; ci < 4; ++ci) {
    float4 o4; o4.x = acc[ci][0]; o4.y = acc[ci][1]; o4.z = acc[ci][2]; o4.w = acc[ci][3];
    *reinterpret_cast<float4*>(eo + (c0 + ci) * 64 + d0) = o4;
  }
}

// ---------------------------------------------------------------------------
// attn_cam[i,b][c][d] = sum_j softmax_d(e_cam[i,j,b,c,:])[d]     grid 24
// ---------------------------------------------------------------------------
__global__ __launch_bounds__(256) void acam_kernel(
    const float* __restrict__ ecam, float* __restrict__ acam)
{
  const int bx = blockIdx.x;
  const int b = bx & 7, i = bx >> 3;
  const int t = threadIdx.x;
  const int c = t >> 2, seg = t & 3;
  float acc[16] = {};
#pragma unroll
  for (int j = 0; j < 3; ++j) {
    const float* e = ecam + (size_t)((i * 3 + j) * 8 + b) * 4096 + c * 64 + seg * 16;
    float ev[16];
#pragma unroll
    for (int r = 0; r < 4; ++r) {
      const float4 v4 = *reinterpret_cast<const float4*>(e + r * 4);
      ev[4 * r] = v4.x; ev[4 * r + 1] = v4.y; ev[4 * r + 2] = v4.z; ev[4 * r + 3] = v4.w;
    }
    float mx = ev[0];
#pragma unroll
    for (int r = 1; r < 16; ++r) mx = fmaxf(mx, ev[r]);
    mx = fmaxf(mx, __shfl_xor(mx, 1, 4));
    mx = fmaxf(mx, __shfl_xor(mx, 2, 4));
    float pv[16], ss = 0.f;
#pragma unroll
    for (int r = 0; r < 16; ++r) { pv[r] = __expf(ev[r] - mx); ss += pv[r]; }
    ss += __shfl_xor(ss, 1, 4);
    ss += __shfl_xor(ss, 2, 4);
    const float rc = 1.f / ss;
#pragma unroll
    for (int r = 0; r < 16; ++r) acc[r] += pv[r] * rc;
  }
  float* ao = acam + (size_t)(i * 8 + b) * 4096 + c * 64 + seg * 16;
#pragma unroll
  for (int r = 0; r < 4; ++r) {
    float4 o4; o4.x = acc[4 * r]; o4.y = acc[4 * r + 1]; o4.z = acc[4 * r + 2]; o4.w = acc[4 * r + 3];
    *reinterpret_cast<float4*>(ao + r * 4) = o4;
  }
}

// ---------------------------------------------------------------------------
// PAM, flash-style, barrier-free: ONE WAVE owns one 16-query tile.
// grid 1536, 64 threads. Per j: 8 x 128-m chunks with online softmax
// (running max, oacc rescale, per-lane partial den); P exchanged through a
// wave-private 4KB swizzled LDS scratch (same-wave ds ops -> no barriers).
// Per-j normalization applied at j end: oat += oacc / den_j.
// ---------------------------------------------------------------------------
__global__ __launch_bounds__(64, 2) void pam_flash_kernel(
    const float* __restrict__ q, const unsigned short* __restrict__ kT,
    const unsigned short* __restrict__ vh,
    const float* __restrict__ ocam, float* __restrict__ tgts, float* __restrict__ esum_pam)
{
  const int tile = blockIdx.x;        // 0..1535
  const int qt = tile & 63;
  const int b  = (tile >> 6) & 7;
  const int i  = tile >> 9;
  const int n0 = qt * 16;
  const int lane = threadIdx.x & 63;
  const int nl = lane & 15;           // query col within tile
  const int g16 = lane >> 4;          // k-group

  __shared__ unsigned short Pw[16 * 128];   // 4 KB, [n][mloc ^ (8n)] fp16

  const size_t ibo = (size_t)(i * 8 + b) * PLANE;

  // Q B-fragments: direct strided global loads (16 scalars/lane)
  const float* qg = q + ibo + n0 + nl;
  h8 qh[2];
#pragma unroll
  for (int ks = 0; ks < 2; ++ks) {
#pragma unroll
    for (int idx = 0; idx < 8; ++idx)
      qh[ks][idx] = (_Float16)qg[(size_t)(ks * 32 + g16 * 8 + idx) * N_];
  }

  f32x4 oat[4];
#pragma unroll
  for (int ct = 0; ct < 4; ++ct) oat[ct] = f32x4{0.f, 0.f, 0.f, 0.f};

#pragma unroll 1
  for (int j = 0; j < 3; ++j) {
    const unsigned short* kj = kT + ((size_t)(j * 8 + b) * 1024 + nl) * 64 + g16 * 8;
    float runmx = -3.4e38f, den = 0.f, es = 0.f;
    f32x4 oacc[4];
#pragma unroll
    for (int ct = 0; ct < 4; ++ct) oacc[ct] = f32x4{0.f, 0.f, 0.f, 0.f};

#pragma unroll 1
    for (int mc = 0; mc < 8; ++mc) {
      const unsigned short* kp = kj + (size_t)(mc * 128) * 64;

      // QK chunk: 128 m x 16 n
      f32x4 l4[8];
#pragma unroll
      for (int tt = 0; tt < 8; ++tt) {
        const int off = tt * 1024;    // 16 m rows * 64 c
        const uint4 k0 = *reinterpret_cast<const uint4*>(kp + off);
        const uint4 k1 = *reinterpret_cast<const uint4*>(kp + off + 32);
        f32x4 a = f32x4{0.f, 0.f, 0.f, 0.f};
        a = mfmah(bch8(k0), qh[0], a);
        a = mfmah(bch8(k1), qh[1], a);
        l4[tt] = a;
      }

      // chunk stats
      float cm = -3.4e38f, cs = 0.f;
#pragma unroll
      for (int tt = 0; tt < 8; ++tt) {
#pragma unroll
        for (int r = 0; r < 4; ++r) { cm = fmaxf(cm, l4[tt][r]); cs += l4[tt][r]; }
      }
      es += cs;
      cm = fmaxf(cm, __shfl_xor(cm, 16, 64));
      cm = fmaxf(cm, __shfl_xor(cm, 32, 64));
      const float newmx = fmaxf(runmx, cm);
      const float sc = __expf(runmx - newmx);

      float psum = 0.f;
#pragma unroll
      for (int tt = 0; tt < 8; ++tt) {
#pragma unroll
        for (int r = 0; r < 4; ++r) {
          l4[tt][r] = __expf(l4[tt][r] - newmx);
          psum += l4[tt][r];
        }
      }
      den = den * sc + psum;
#pragma unroll
      for (int ct = 0; ct < 4; ++ct)
#pragma unroll
        for (int r = 0; r < 4; ++r) oacc[ct][r] *= sc;

      // stage P (fp16, swizzled) -- wave-local, no barrier
#pragma unroll
      for (int tt = 0; tt < 8; ++tt) {
        const int ml = tt * 16 + g16 * 4;
        uint2 w2;
        w2.x = pkh(l4[tt][0], l4[tt][1]);
        w2.y = pkh(l4[tt][2], l4[tt][3]);
        *reinterpret_cast<uint2*>(&Pw[nl * 128 + (ml ^ (nl * 8))]) = w2;
      }

      // PV chunk: oacc[ct] += V[ct-tile][mchunk] @ P
      const unsigned short* vgc = vh + ibo + (size_t)nl * 1024 + mc * 128 + g16 * 8;
#pragma unroll 2
      for (int ks = 0; ks < 4; ++ks) {
        const h8 pf = bch8(*reinterpret_cast<const uint4*>(
            &Pw[nl * 128 + ((ks * 32 + g16 * 8) ^ (nl * 8))]));
#pragma unroll
        for (int ct = 0; ct < 4; ++ct) {
          const uint4 va = *reinterpret_cast<const uint4*>(vgc + (size_t)ct * 16384 + ks * 32);
          oacc[ct] = mfmah(bch8(va), pf, oacc[ct]);
        }
      }
      runmx = newmx;
    }

    // finish j: cross-lane den, normalize, accumulate
    den += __shfl_xor(den, 16, 64);
    den += __shfl_xor(den, 32, 64);
    const float rs = 1.f / den;
#pragma unroll
    for (int ct = 0; ct < 4; ++ct)
#pragma unroll
      for (int r = 0; r < 4; ++r) oat[ct][r] += rs * oacc[ct][r];

    es = wred_sum(es);
    if (lane == 0) atomicAdd(esum_pam + i * 3 + j, es);
  }

  // epilogue: fuse with out_cam, write tgts even slot
  const float* og = ocam + ibo;
  float* outg = tgts + (size_t)(2 * i * 8 + b) * PLANE;
#pragma unroll
  for (int ct = 0; ct < 4; ++ct) {
#pragma unroll
    for (int r = 0; r < 4; ++r) {
      const int c = ct * 16 + g16 * 4 + r;
      const int idx = c * N_ + n0 + nl;
      outg[idx] = 0.5f * (oat[ct][r] + og[idx]);
    }
  }
}

// ---------------------------------------------------------------------------
// alpha[i][j] = 0.5*(softmax_j(mean e_pam) + softmax_j(mean e_cam))
// ---------------------------------------------------------------------------
__global__ void alpha_kernel(const float* __restrict__ esum, float* __restrict__ alpha)
{
  const int t = threadIdx.x;
  if (t >= 9) return;
  const int i = t / 3, j = t % 3;
  float p[3], c[3];
#pragma unroll
  for (int jj = 0; jj < 3; ++jj) {
    p[jj] = esum[i * 3 + jj] * (1.0f / 8388608.0f);
    c[jj] = esum[9 + i * 3 + jj] * (1.0f / 32768.0f);
  }
  const float mp = fmaxf(p[0], fmaxf(p[1], p[2]));
  const float mc = fmaxf(c[0], fmaxf(c[1], c[2]));
  float sp = 0.f, sc = 0.f;
#pragma unroll
  for (int jj = 0; jj < 3; ++jj) { sp += __expf(p[jj] - mp); sc += __expf(c[jj] - mc); }
  alpha[t] = 0.5f * (__expf(p[j] - mp) / sp + __expf(c[j] - mc) / sc);
}

// ---------------------------------------------------------------------------
extern "C" void kernel_launch(void* const* d_in, const int* in_sizes, int n_in,
                              void* d_out, int out_size, void* d_ws, size_t ws_size,
                              hipStream_t stream)
{
  const float* src0 = (const float*)d_in[0];
  const float* src1 = (const float*)d_in[1];
  const float* src2 = (const float*)d_in[2];
  const float* tgt0 = (const float*)d_in[3];
  const float* tgt1 = (const float*)d_in[4];
  const float* tgt2 = (const float*)d_in[5];
  const float* fs0_w = (const float*)d_in[6];  const float* fs0_b = (const float*)d_in[7];
  const float* fs1_w = (const float*)d_in[8];  const float* fs1_b = (const float*)d_in[9];
  const float* fs2_w = (const float*)d_in[10]; const float* fs2_b = (const float*)d_in[11];
  const float* ft0_w = (const float*)d_in[12]; const float* ft0_b = (const float*)d_in[13];
  const float* ft1_w = (const float*)d_in[14]; const float* ft1_b = (const float*)d_in[15];
  const float* ft2_w = (const float*)d_in[16]; const float* ft2_b = (const float*)d_in[17];
  const float* pq_w = (const float*)d_in[18];  const float* pq_b = (const float*)d_in[19];
  const float* pk_w = (const float*)d_in[20];  const float* pk_b = (const float*)d_in[21];
  const float* pv_w = (const float*)d_in[22];  const float* pv_b = (const float*)d_in[23];
  const float* cv_w = (const float*)d_in[24];  const float* cv_b = (const float*)d_in[25];

  float* out = (float*)d_out;
  float* S     = out;                 // srcs region doubles as S storage
  float* alpha = out + SZ;            // 9 floats
  float* tgts  = out + SZ + 9;        // [2L][B][PLANE]

  float* ws   = (float*)d_ws;
  float* T    = ws;
  float* qb   = ws + (size_t)SZ;
  float* kb   = ws + (size_t)2 * SZ;
  float* vb   = ws + (size_t)3 * SZ;
  float* vcb  = ws + (size_t)4 * SZ;
  float* ocam = ws + (size_t)5 * SZ;
  float* ecam = ws + (size_t)6 * SZ;                 // 294912
  float* acam = ws + (size_t)6 * SZ + 294912;        // 98304
  float* esum = ws + (size_t)6 * SZ + 393216;        // 18 (pam 9, cam 9)

  // fp16 buffers appended after the fp32 region
  unsigned short* kT = (unsigned short*)(ws + (size_t)6 * SZ + 393216 + 256);
  unsigned short* vh = kT + (size_t)24 * PLANE;
  unsigned short* wh = vh + (size_t)24 * PLANE;      // 98304 ushorts
  unsigned short* w9s = wh + 98304;                  // 73728 ushorts
  unsigned short* w9t = w9s + 73728;

  // Overlays in qb..vcb (each consumed before the next producer writes):
  unsigned short* inTs = (unsigned short*)qb;        // 8*4096*128
  unsigned short* inTt = inTs + 4194304;
  unsigned short* Xs1 = (unsigned short*)qb;         // 8x1024x256
  unsigned short* Xs2 = Xs1 + 2097152;               // 8x1024x512
  unsigned short* Xt1 = Xs1 + 6291456;               // 8x1024x256
  unsigned short* Xt2 = Xs1 + 8388608;               // 8x1024x512

  hipMemsetAsync(esum, 0, 18 * sizeof(float), stream);

  // conv0 via MFMA: channels-last fp16 inputs + fp16 tap weights
  w9conv_kernel<<<576, 256, 0, stream>>>(fs0_w, ft0_w, w9s, w9t);
  xprep_kernel<<<dim3(8, 2, 64), 256, 0, stream>>>(src0, inTs, 128, 4096);
  xprep_kernel<<<dim3(8, 2, 64), 256, 0, stream>>>(tgt0, inTt, 128, 4096);
  conv0_mfma_kernel<<<dim3(32, 8, 2), 256, 0, stream>>>(
      inTs, inTt, w9s, w9t, fs0_b, ft0_b, S, T, tgts + (size_t)1 * BPL);

  // fp16 fit GEMMs (overwrite the inT overlay with Xh)
  xprep_kernel<<<dim3(8, 4, 16), 256, 0, stream>>>(src1, Xs1, 256, 1024);
  xprep_kernel<<<dim3(8, 8, 16), 256, 0, stream>>>(src2, Xs2, 512, 1024);
  xprep_kernel<<<dim3(8, 4, 16), 256, 0, stream>>>(tgt1, Xt1, 256, 1024);
  xprep_kernel<<<dim3(8, 8, 16), 256, 0, stream>>>(tgt2, Xt2, 512, 1024);
  whconv_kernel<<<192, 256, 0, stream>>>(fs1_w, fs2_w, ft1_w, ft2_w, wh);
  gemmh_kernel<<<dim3(16, 16), 256, 0, stream>>>(
      Xs1, Xt1, wh, wh + 49152, fs1_b, ft1_b,
      S + BPL, T + BPL, tgts + (size_t)3 * BPL, 256);
  gemmh_kernel<<<dim3(16, 16), 256, 0, stream>>>(
      Xs2, Xt2, wh + 16384, wh + 65536, fs2_b, ft2_b,
      S + 2 * BPL, T + 2 * BPL, tgts + (size_t)5 * BPL, 512);

  // All 4 projections in one launch (writes qb..vcb, overwriting the overlay)
  proj_kernel<<<dim3(24, 16, 4), 256, 0, stream>>>(
      T, S, pq_w, pk_w, pv_w, cv_w, pq_b, pk_b, pv_b, cv_b, qb);

  // Pack k (transposed fp16) and v (fp16) for the MFMA attention
  kprep_kernel<<<dim3(24, 4), 256, 0, stream>>>(kb, vb, kT, vh);

  // CAM
  ecam_kernel<<<72, 256, 0, stream>>>(T, S, ecam, esum + 9);
  acam_kernel<<<24, 256, 0, stream>>>(ecam, acam);
  gemm64_kernel<<<dim3(24, 16), 256, 0, stream>>>(acam, 4096, 1, vcb, PLANE, ocam, PLANE,
                                                  nullptr, 0, 64);

  // PAM + fuse (writes tgts even slots = 0.5*(out_pam + out_cam))
  pam_flash_kernel<<<1536, 64, 0, stream>>>(qb, kT, vh, ocam, tgts, esum);

  alpha_kernel<<<1, 64, 0, stream>>>(esum, alpha);
}

// Round 14
// 327.799 us; speedup vs baseline: 1.2694x; 1.2694x over previous
//
#include <hip/hip_runtime.h>

// Problem constants
static constexpr int L_ = 3, B_ = 8, C_ = 64, N_ = 1024;
static constexpr int PLANE = C_ * N_;       // 65536
static constexpr int SZ    = L_ * B_ * PLANE; // 1572864
static constexpr int BPL   = B_ * PLANE;    // 524288

#define DI __device__ __forceinline__

typedef _Float16 h8 __attribute__((ext_vector_type(8)));   // 8 fp16 (MFMA A/B frag)
typedef __attribute__((ext_vector_type(4))) float f32x4;   // MFMA C/D frag
typedef unsigned int uint32;

DI float wred_sum(float v) {
#pragma unroll
  for (int m = 1; m < 64; m <<= 1) v += __shfl_xor(v, m, 64);
  return v;
}

DI unsigned short f2h(float f) {
  return __builtin_bit_cast(unsigned short, (_Float16)f);
}
DI float h2f(unsigned short h) {
  return (float)__builtin_bit_cast(_Float16, h);
}
DI uint32 pkh(float a, float b) {
  return (uint32)f2h(a) | ((uint32)f2h(b) << 16);
}
DI h8 bch8(uint4 v) { return __builtin_bit_cast(h8, v); }

DI f32x4 mfmah(h8 a, h8 b, f32x4 c) {
  return __builtin_amdgcn_mfma_f32_16x16x32_f16(a, b, c, 0, 0, 0);
}

// ---------------------------------------------------------------------------
// xprep: transpose+convert in[g][K][N] fp32 -> out[g][N][K] fp16.
// grid (8, K/64, N/64); 64x64 tile per block.
// ---------------------------------------------------------------------------
__global__ __launch_bounds__(256) void xprep_kernel(
    const float* __restrict__ in, unsigned short* __restrict__ out, int K, int N)
{
  const int g = blockIdx.x, kc = blockIdx.y, nc = blockIdx.z;
  const int t = threadIdx.x;
  __shared__ float tl[64][65];
  const float* ing = in + (size_t)g * K * N + (size_t)(kc * 64) * N + nc * 64;
#pragma unroll 4
  for (int r = 0; r < 16; ++r) {
    const int kk = r * 4 + (t >> 6);
    tl[kk][t & 63] = ing[(size_t)kk * N + (t & 63)];
  }
  __syncthreads();
  const int mm = t >> 2, kseg = (t & 3) * 16;
  uint32 hw[8];
#pragma unroll
  for (int ii = 0; ii < 8; ++ii)
    hw[ii] = pkh(tl[kseg + 2 * ii][mm], tl[kseg + 2 * ii + 1][mm]);
  unsigned short* o = out + ((size_t)g * N + nc * 64 + mm) * K + kc * 64 + kseg;
  uint4 h0; h0.x = hw[0]; h0.y = hw[1]; h0.z = hw[2]; h0.w = hw[3];
  uint4 h1; h1.x = hw[4]; h1.y = hw[5]; h1.z = hw[6]; h1.w = hw[7];
  *reinterpret_cast<uint4*>(o)     = h0;
  *reinterpret_cast<uint4*>(o + 8) = h1;
}

// ---------------------------------------------------------------------------
// w9conv: conv weights w[co][ci][k9] fp32 -> w9[k9][co][ci] fp16 (both s,t).
// grid 576.
// ---------------------------------------------------------------------------
__global__ __launch_bounds__(256) void w9conv_kernel(
    const float* __restrict__ w_s, const float* __restrict__ w_t,
    unsigned short* __restrict__ w9_s, unsigned short* __restrict__ w9_t)
{
  const int e = blockIdx.x * 256 + threadIdx.x;  // 0..147455
  const float* w = (e < 73728) ? w_s : w_t;
  unsigned short* o = (e < 73728) ? w9_s : w9_t;
  const int le = (e < 73728) ? e : e - 73728;
  const int ci = le & 127;
  const int q = le >> 7;
  const int co = q & 63;
  const int k9 = q >> 6;
  o[le] = f2h(w[(co * 128 + ci) * 9 + k9]);
}

// ---------------------------------------------------------------------------
// conv0 via MFMA: 3x3 s2 p1, 128->64, using channels-last fp16 inT[b][pix][ci]
// and w9[tap][co][ci]. grid (32 out-rows, 8 b, 2 st), 256 thr = 4 waves.
// ---------------------------------------------------------------------------
__global__ __launch_bounds__(256) void conv0_mfma_kernel(
    const unsigned short* __restrict__ inT_s, const unsigned short* __restrict__ inT_t,
    const unsigned short* __restrict__ w9_s, const unsigned short* __restrict__ w9_t,
    const float* __restrict__ b_s, const float* __restrict__ b_t,
    float* __restrict__ Sout, float* __restrict__ Tout, float* __restrict__ tdup)
{
  const int yr = blockIdx.x;          // output row 0..31
  const int b  = blockIdx.y;
  const int st = blockIdx.z;
  const unsigned short* inT = st ? inT_t : inT_s;
  const unsigned short* w9  = st ? w9_t  : w9_s;
  const float* bias = st ? b_t : b_s;
  float* outA = st ? Tout : Sout;

  const int t = threadIdx.x, lane = t & 63;
  const int ct = t >> 6;              // co-tile
  const int nl = lane & 15, g16 = lane >> 4;
  const unsigned short* inb = inT + (size_t)b * (4096 * 128);
  const unsigned short* wbase = w9 + (size_t)(ct * 16 + nl) * 128;

  f32x4 acc0 = f32x4{0.f, 0.f, 0.f, 0.f};
  f32x4 acc1 = f32x4{0.f, 0.f, 0.f, 0.f};
  const uint4 zz = uint4{0u, 0u, 0u, 0u};

#pragma unroll 1
  for (int tap = 0; tap < 9; ++tap) {
    const int ky = tap / 3, kx = tap - 3 * (tap / 3);
    const int py = 2 * yr - 1 + ky;                 // [-1, 63]
    const int px0 = 2 * nl - 1 + kx;                // nt=0: x = nl
    const int px1 = px0 + 32;                       // nt=1: x = 16+nl (>=31)
    const bool v0 = (py >= 0) && (px0 >= 0);
    const bool v1 = (py >= 0);
    const unsigned short* prow = inb + (ptrdiff_t)py * (64 * 128);
#pragma unroll
    for (int ks = 0; ks < 4; ++ks) {
      const h8 a = bch8(*reinterpret_cast<const uint4*>(
          wbase + tap * 8192 + ks * 32 + g16 * 8));
      const uint4 bv0 = v0 ? *reinterpret_cast<const uint4*>(
                                 prow + px0 * 128 + ks * 32 + g16 * 8) : zz;
      const uint4 bv1 = v1 ? *reinterpret_cast<const uint4*>(
                                 prow + px1 * 128 + ks * 32 + g16 * 8) : zz;
      acc0 = mfmah(a, bch8(bv0), acc0);
      acc1 = mfmah(a, bch8(bv1), acc1);
    }
  }

  const int yb = yr * 32;
#pragma unroll
  for (int r = 0; r < 4; ++r) {
    const int co = ct * 16 + g16 * 4 + r;
    const float bv = bias[co];
    const int idx = (b * 64 + co) * 1024 + yb + nl;
    const float o0 = acc0[r] + bv;
    const float o1 = acc1[r] + bv;
    outA[idx] = o0; outA[idx + 16] = o1;
    if (st) { tdup[idx] = o0; tdup[idx + 16] = o1; }
  }
}

// ---------------------------------------------------------------------------
// Generic fp32 out[g][64][1024] = W[g/wdiv][64][K] @ X[g][K][1024] + bias
// (kept for attn_cam @ vc)
// ---------------------------------------------------------------------------
__global__ __launch_bounds__(256) void gemm64_kernel(
    const float* __restrict__ W, int wstride, int wdiv,
    const float* __restrict__ X, int xstride,
    float* __restrict__ out, int ostride,
    const float* __restrict__ bias, int bstride,
    int K)
{
  const int g  = blockIdx.x;
  const int n0 = blockIdx.y * 64;
  const float* Wg = W + (size_t)(g / wdiv) * wstride;
  const float* Xg = X + (size_t)g * xstride;
  const int t = threadIdx.x;
  __shared__ float Xs[32][64];
  __shared__ float Ws[32][64];
  const int tn = t & 15, cgp = t >> 4;
  const int n4 = tn * 4, co4 = cgp * 4;
  float acc[4][4] = {};

  for (int k0 = 0; k0 < K; k0 += 32) {
    {
      const int kk = t >> 4;
      const int nn = (t & 15) * 4;
      *reinterpret_cast<float4*>(&Xs[kk][nn]) =
          *reinterpret_cast<const float4*>(Xg + (size_t)(k0 + kk) * N_ + n0 + nn);
      *reinterpret_cast<float4*>(&Xs[kk + 16][nn]) =
          *reinterpret_cast<const float4*>(Xg + (size_t)(k0 + kk + 16) * N_ + n0 + nn);
    }
    {
      const int co = t & 63, q4 = t >> 6;
      const float* wp = Wg + (size_t)co * K + k0 + q4 * 8;
      const float4 a = *reinterpret_cast<const float4*>(wp);
      const float4 c = *reinterpret_cast<const float4*>(wp + 4);
      const int kb = q4 * 8;
      Ws[kb + 0][co] = a.x; Ws[kb + 1][co] = a.y; Ws[kb + 2][co] = a.z; Ws[kb + 3][co] = a.w;
      Ws[kb + 4][co] = c.x; Ws[kb + 5][co] = c.y; Ws[kb + 6][co] = c.z; Ws[kb + 7][co] = c.w;
    }
    __syncthreads();
#pragma unroll
    for (int kk = 0; kk < 32; ++kk) {
      const float4 xv = *reinterpret_cast<const float4*>(&Xs[kk][n4]);
      const float4 wv = *reinterpret_cast<const float4*>(&Ws[kk][co4]);
      const float xa[4] = {xv.x, xv.y, xv.z, xv.w};
      const float wa[4] = {wv.x, wv.y, wv.z, wv.w};
#pragma unroll
      for (int a = 0; a < 4; ++a)
#pragma unroll
        for (int b2 = 0; b2 < 4; ++b2)
          acc[a][b2] = fmaf(wa[a], xa[b2], acc[a][b2]);
    }
    __syncthreads();
  }

  float bv[4] = {0.f, 0.f, 0.f, 0.f};
  if (bias) {
    const float* bg = bias + (size_t)(g / wdiv) * bstride;
    bv[0] = bg[co4]; bv[1] = bg[co4 + 1]; bv[2] = bg[co4 + 2]; bv[3] = bg[co4 + 3];
  }
#pragma unroll
  for (int ii = 0; ii < 4; ++ii) {
    float4 o4;
    o4.x = acc[ii][0] + bv[ii]; o4.y = acc[ii][1] + bv[ii];
    o4.z = acc[ii][2] + bv[ii]; o4.w = acc[ii][3] + bv[ii];
    *reinterpret_cast<float4*>(out + (size_t)g * ostride + (co4 + ii) * N_ + n0 + n4) = o4;
  }
}

// ---------------------------------------------------------------------------
// proj: all 4 projections (q,k,v,vc) in ONE launch. grid (24, 16, 4).
// ---------------------------------------------------------------------------
__global__ __launch_bounds__(256) void proj_kernel(
    const float* __restrict__ Tm, const float* __restrict__ Sm,
    const float* __restrict__ wq, const float* __restrict__ wk,
    const float* __restrict__ wv2, const float* __restrict__ wc,
    const float* __restrict__ bq, const float* __restrict__ bk,
    const float* __restrict__ bv2, const float* __restrict__ bc,
    float* __restrict__ outbase)
{
  const int g  = blockIdx.x;          // i*8+b
  const int n0 = blockIdx.y * 64;
  const int z  = blockIdx.z;          // 0=q 1=k 2=v 3=vc
  const float* W  = (z == 0) ? wq : (z == 1) ? wk : (z == 2) ? wv2 : wc;
  const float* bi = (z == 0) ? bq : (z == 1) ? bk : (z == 2) ? bv2 : bc;
  const float* Xg = ((z == 1) ? Sm : Tm) + (size_t)g * PLANE;
  float* out = outbase + (size_t)z * SZ + (size_t)g * PLANE;
  const float* Wg = W + (g >> 3) * 4096;
  const float* bg = bi + (g >> 3) * 64;

  const int t = threadIdx.x;
  __shared__ float Xs[32][64];
  __shared__ float Ws[32][64];
  const int tn = t & 15, cgp = t >> 4;
  const int n4 = tn * 4, co4 = cgp * 4;
  float acc[4][4] = {};

#pragma unroll 1
  for (int k0 = 0; k0 < 64; k0 += 32) {
    {
      const int kk = t >> 4;
      const int nn = (t & 15) * 4;
      *reinterpret_cast<float4*>(&Xs[kk][nn]) =
          *reinterpret_cast<const float4*>(Xg + (size_t)(k0 + kk) * N_ + n0 + nn);
      *reinterpret_cast<float4*>(&Xs[kk + 16][nn]) =
          *reinterpret_cast<const float4*>(Xg + (size_t)(k0 + kk + 16) * N_ + n0 + nn);
    }
    {
      const int co = t & 63, q4 = t >> 6;
      const float* wp = Wg + (size_t)co * 64 + k0 + q4 * 8;
      const float4 a = *reinterpret_cast<const float4*>(wp);
      const float4 c = *reinterpret_cast<const float4*>(wp + 4);
      const int kb = q4 * 8;
      Ws[kb + 0][co] = a.x; Ws[kb + 1][co] = a.y; Ws[kb + 2][co] = a.z; Ws[kb + 3][co] = a.w;
      Ws[kb + 4][co] = c.x; Ws[kb + 5][co] = c.y; Ws[kb + 6][co] = c.z; Ws[kb + 7][co] = c.w;
    }
    __syncthreads();
#pragma unroll
    for (int kk = 0; kk < 32; ++kk) {
      const float4 xv = *reinterpret_cast<const float4*>(&Xs[kk][n4]);
      const float4 wv = *reinterpret_cast<const float4*>(&Ws[kk][co4]);
      const float xa[4] = {xv.x, xv.y, xv.z, xv.w};
      const float wa[4] = {wv.x, wv.y, wv.z, wv.w};
#pragma unroll
      for (int a = 0; a < 4; ++a)
#pragma unroll
        for (int b2 = 0; b2 < 4; ++b2)
          acc[a][b2] = fmaf(wa[a], xa[b2], acc[a][b2]);
    }
    __syncthreads();
  }

#pragma unroll
  for (int ii = 0; ii < 4; ++ii) {
    const float bv = bg[co4 + ii];
    float4 o4;
    o4.x = acc[ii][0] + bv; o4.y = acc[ii][1] + bv;
    o4.z = acc[ii][2] + bv; o4.w = acc[ii][3] + bv;
    *reinterpret_cast<float4*>(out + (co4 + ii) * N_ + n0 + n4) = o4;
  }
}

// ---------------------------------------------------------------------------
// whconv: fit-GEMM weights to fp16: wh1s@0, wh2s@16384, wh1t@49152, wh2t@65536
// ---------------------------------------------------------------------------
__global__ __launch_bounds__(256) void whconv_kernel(
    const float* __restrict__ w1s, const float* __restrict__ w2s,
    const float* __restrict__ w1t, const float* __restrict__ w2t,
    unsigned short* __restrict__ wh)
{
  const int p = blockIdx.x * 256 + threadIdx.x;  // pair index 0..49151
  const float* in; int local; unsigned short* out;
  if (p < 8192)       { in = w1s; local = p;         out = wh; }
  else if (p < 24576) { in = w2s; local = p - 8192;  out = wh + 16384; }
  else if (p < 32768) { in = w1t; local = p - 24576; out = wh + 49152; }
  else                { in = w2t; local = p - 32768; out = wh + 65536; }
  const float2 v = *reinterpret_cast<const float2*>(in + 2 * local);
  *reinterpret_cast<uint32*>(out + 2 * local) = pkh(v.x, v.y);
}

// ---------------------------------------------------------------------------
// gemmh: fp16 MFMA fit-GEMM. out[g][64co][1024n] = W[64][K] @ Xh[n][K].
// grid (16, 16); g<8 = src, g>=8 = tgt (+dual write).
// ---------------------------------------------------------------------------
__global__ __launch_bounds__(256) void gemmh_kernel(
    const unsigned short* __restrict__ Xa, const unsigned short* __restrict__ Xb,
    const unsigned short* __restrict__ Wa, const unsigned short* __restrict__ Wb,
    const float* __restrict__ ba, const float* __restrict__ bb,
    float* __restrict__ oa, float* __restrict__ ob, float* __restrict__ o2b,
    int K)
{
  const int g = blockIdx.x;
  const bool isb = g >= 8;
  const int gl = g & 7;
  const unsigned short* X = (isb ? Xb : Xa) + (size_t)gl * 1024 * K;
  const unsigned short* W = isb ? Wb : Wa;
  const float* bias = isb ? bb : ba;
  float* out = (isb ? ob : oa) + (size_t)gl * PLANE;
  float* out2 = isb ? o2b + (size_t)gl * PLANE : nullptr;

  const int t = threadIdx.x, lane = t & 63, wv = t >> 6;
  const int nl = lane & 15, g16 = lane >> 4;
  const int n0w = blockIdx.y * 64 + wv * 16;

  const unsigned short* xp = X + (size_t)(n0w + nl) * K + g16 * 8;
  const unsigned short* wp = W + (size_t)nl * K + g16 * 8;

  f32x4 acc[4];
#pragma unroll
  for (int ct = 0; ct < 4; ++ct) acc[ct] = f32x4{0.f, 0.f, 0.f, 0.f};

#pragma unroll 4
  for (int kk = 0; kk < K; kk += 32) {
    const h8 a = bch8(*reinterpret_cast<const uint4*>(xp + kk));
#pragma unroll
    for (int ct = 0; ct < 4; ++ct) {
      const h8 bfr = bch8(*reinterpret_cast<const uint4*>(wp + (size_t)ct * 16 * K + kk));
      acc[ct] = mfmah(a, bfr, acc[ct]);
    }
  }

#pragma unroll
  for (int ct = 0; ct < 4; ++ct) {
    const int co = ct * 16 + nl;
    const float bv = bias[co];
    float4 o4;
    o4.x = acc[ct][0] + bv; o4.y = acc[ct][1] + bv;
    o4.z = acc[ct][2] + bv; o4.w = acc[ct][3] + bv;
    const int idx = co * N_ + n0w + g16 * 4;
    *reinterpret_cast<float4*>(out + idx) = o4;
    if (out2) {
      out2[idx] = o4.x; out2[idx + 1] = o4.y;
      out2[idx + 2] = o4.z; out2[idx + 3] = o4.w;
    }
  }
}

// ---------------------------------------------------------------------------
// kprep: k[g][64c][1024m] -> kT[g][1024m][64c] (fp16); v[g] -> vh[g] (fp16).
// grid (24, 4)
// ---------------------------------------------------------------------------
__global__ __launch_bounds__(256) void kprep_kernel(
    const float* __restrict__ kb, const float* __restrict__ vb,
    unsigned short* __restrict__ kT, unsigned short* __restrict__ vh)
{
  const int g = blockIdx.x;
  const int ch = blockIdx.y;
  const int t = threadIdx.x;
  const float* kg = kb + (size_t)g * PLANE;
  __shared__ float tl[64][65];

#pragma unroll 1
  for (int tile = 0; tile < 4; ++tile) {
    const int m0 = ch * 256 + tile * 64;
    __syncthreads();
#pragma unroll 4
    for (int r = 0; r < 16; ++r) {
      const int c = r * 4 + (t >> 6);
      tl[c][t & 63] = kg[c * N_ + m0 + (t & 63)];
    }
    __syncthreads();
    const int mm = t >> 2, cseg = (t & 3) * 16;
    uint32 hw[8];
#pragma unroll
    for (int ii = 0; ii < 8; ++ii)
      hw[ii] = pkh(tl[cseg + 2 * ii][mm], tl[cseg + 2 * ii + 1][mm]);
    const size_t o = ((size_t)g * 1024 + m0 + mm) * 64 + cseg;
    uint4 h0; h0.x = hw[0]; h0.y = hw[1]; h0.z = hw[2]; h0.w = hw[3];
    uint4 h1; h1.x = hw[4]; h1.y = hw[5]; h1.z = hw[6]; h1.w = hw[7];
    *reinterpret_cast<uint4*>(kT + o)     = h0;
    *reinterpret_cast<uint4*>(kT + o + 8) = h1;
  }

  const float* vg = vb + (size_t)g * PLANE;
  unsigned short* vo = vh + (size_t)g * PLANE;
  for (int e8 = ch * 2048 + t; e8 < (ch + 1) * 2048; e8 += 256) {
    const float4 a = *reinterpret_cast<const float4*>(vg + (size_t)e8 * 8);
    const float4 b = *reinterpret_cast<const float4*>(vg + (size_t)e8 * 8 + 4);
    uint4 u;
    u.x = pkh(a.x, a.y); u.y = pkh(a.z, a.w);
    u.z = pkh(b.x, b.y); u.w = pkh(b.z, b.w);
    *reinterpret_cast<uint4*>(vo + (size_t)e8 * 8) = u;
  }
}

// ---------------------------------------------------------------------------
// e_cam[i,j,b][c][d] = sum_n T[i,b,c,n] * S[j,b,d,n];  also atomic raw-sum.
// ---------------------------------------------------------------------------
__global__ __launch_bounds__(256) void ecam_kernel(
    const float* __restrict__ T, const float* __restrict__ S,
    float* __restrict__ ecam, float* __restrict__ esum_cam)
{
  const int bx = blockIdx.x;
  const int b = bx & 7;
  const int j = (bx >> 3) % 3;
  const int i = bx / 24;
  const float* Tg = T + (size_t)(i * 8 + b) * PLANE;
  const float* Sg = S + (size_t)(j * 8 + b) * PLANE;
  const int t = threadIdx.x;
  __shared__ float Ts[64 * 68];
  __shared__ float Ss[64 * 68];
  __shared__ float rs[4];
  float acc[4][4] = {};
  const int c0 = (t & 15) * 4, d0 = (t >> 4) * 4;

  for (int nb = 0; nb < 1024; nb += 64) {
    __syncthreads();
    {
      const int nn = t & 63, rb = t >> 6;
#pragma unroll
      for (int r = 0; r < 16; ++r) {
        const int row = rb * 16 + r;
        Ts[nn * 68 + row] = Tg[row * N_ + nb + nn];
        Ss[nn * 68 + row] = Sg[row * N_ + nb + nn];
      }
    }
    __syncthreads();
#pragma unroll 8
    for (int nn = 0; nn < 64; ++nn) {
      const float4 tv = *reinterpret_cast<const float4*>(&Ts[nn * 68 + c0]);
      const float4 sv = *reinterpret_cast<const float4*>(&Ss[nn * 68 + d0]);
      const float ta[4] = {tv.x, tv.y, tv.z, tv.w};
      const float sa[4] = {sv.x, sv.y, sv.z, sv.w};
#pragma unroll
      for (int ci = 0; ci < 4; ++ci)
#pragma unroll
        for (int di = 0; di < 4; ++di)
          acc[ci][di] = fmaf(ta[ci], sa[di], acc[ci][di]);
    }
  }
  float s = 0.f;
#pragma unroll
  for (int ci = 0; ci < 4; ++ci)
#pragma unroll
    for (int di = 0; di < 4; ++di) s += acc[ci][di];
  s = wred_sum(s);
  if ((t & 63) == 0) rs[t >> 6] = s;
  __syncthreads();
  if (t == 0) atomicAdd(esum_cam + i * 3 + j, rs[0] + rs[1] + rs[2] + rs[3]);

  float* eo = ecam + (size_t)((i * 3 + j) * 8 + b) * 4096;
#pragma unroll
  for (int ci = 0; ci < 4; ++ci) {
    float4 o4; o4.x = acc[ci][0]; o4.y = acc[ci][1]; o4.z = acc[ci][2]; o4.w = acc[ci][3];
    *reinterpret_cast<float4*>(eo + (c0 + ci) * 64 + d0) = o4;
  }
}

// ---------------------------------------------------------------------------
// attn_cam[i,b][c][d] = sum_j softmax_d(e_cam[i,j,b,c,:])[d]     grid 24
// ---------------------------------------------------------------------------
__global__ __launch_bounds__(256) void acam_kernel(
    const float* __restrict__ ecam, float* __restrict__ acam)
{
  const int bx = blockIdx.x;
  const int b = bx & 7, i = bx >> 3;
  const int t = threadIdx.x;
  const int c = t >> 2, seg = t & 3;
  float acc[16] = {};
#pragma unroll
  for (int j = 0; j < 3; ++j) {
    const float* e = ecam + (size_t)((i * 3 + j) * 8 + b) * 4096 + c * 64 + seg * 16;
    float ev[16];
#pragma unroll
    for (int r = 0; r < 4; ++r) {
      const float4 v4 = *reinterpret_cast<const float4*>(e + r * 4);
      ev[4 * r] = v4.x; ev[4 * r + 1] = v4.y; ev[4 * r + 2] = v4.z; ev[4 * r + 3] = v4.w;
    }
    float mx = ev[0];
#pragma unroll
    for (int r = 1; r < 16; ++r) mx = fmaxf(mx, ev[r]);
    mx = fmaxf(mx, __shfl_xor(mx, 1, 4));
    mx = fmaxf(mx, __shfl_xor(mx, 2, 4));
    float pv[16], ss = 0.f;
#pragma unroll
    for (int r = 0; r < 16; ++r) { pv[r] = __expf(ev[r] - mx); ss += pv[r]; }
    ss += __shfl_xor(ss, 1, 4);
    ss += __shfl_xor(ss, 2, 4);
    const float rc = 1.f / ss;
#pragma unroll
    for (int r = 0; r < 16; ++r) acc[r] += pv[r] * rc;
  }
  float* ao = acam + (size_t)(i * 8 + b) * 4096 + c * 64 + seg * 16;
#pragma unroll
  for (int r = 0; r < 4; ++r) {
    float4 o4; o4.x = acc[4 * r]; o4.y = acc[4 * r + 1]; o4.z = acc[4 * r + 2]; o4.w = acc[4 * r + 3];
    *reinterpret_cast<float4*>(ao + r * 4) = o4;
  }
}

// ---------------------------------------------------------------------------
// PAM via fp16 MFMA, 8 waves x 128 m, Psum accumulated in LDS across j and a
// SINGLE PV pass (V is j-independent: v[i,b,c,m]). QK and PV use explicit
// 8-deep register load windows (kf[8]/vf[8] arrays) to force outstanding L2
// loads - pragmas alone left the compiler at 2-4 in flight (VGPR_Count=56).
// grid 1536 = (i, b, qt), 512 threads. 2 barriers/j + 1 before PV.
// ---------------------------------------------------------------------------
__global__ __launch_bounds__(512, 4) void pam_mfma_kernel(
    const float* __restrict__ q, const unsigned short* __restrict__ kT,
    const unsigned short* __restrict__ vh,
    const float* __restrict__ ocam, float* __restrict__ tgts, float* __restrict__ esum_pam)
{
  const int bx = blockIdx.x;
  const int qt = bx & 63;
  const int b  = (bx >> 6) & 7;
  const int i  = bx >> 9;
  const int n0 = qt * 16;
  const int t = threadIdx.x;
  const int lane = t & 63;
  const int wv = t >> 6;             // 0..7
  const int nl = lane & 15;
  const int g16 = lane >> 4;

  __shared__ unsigned short Plds[16 * 1024];  // 32 KB fp16 Psum, [n][m ^ (8n)]
  __shared__ float qlds[64 * 17];             // q staging; aliased as osum later
  __shared__ float redmx[128];
  __shared__ float redse[128];
  __shared__ float redes[8];
  float* osum = qlds;

  const size_t ibo = (size_t)(i * 8 + b) * PLANE;

  const float* qg = q + ibo;
  for (int e = t; e < 1024; e += 512)
    qlds[(e >> 4) * 17 + (e & 15)] = qg[(e >> 4) * N_ + n0 + (e & 15)];
  __syncthreads();

  h8 qh[2];
#pragma unroll
  for (int ks = 0; ks < 2; ++ks) {
#pragma unroll
    for (int idx = 0; idx < 8; ++idx)
      qh[ks][idx] = (_Float16)qlds[(ks * 32 + g16 * 8 + idx) * 17 + nl];
  }

  const int wm0 = wv * 128;
  const int ct = wv & 3;
  const int mh = wv >> 2;

#pragma unroll 1
  for (int j = 0; j < 3; ++j) {
    const unsigned short* kp =
        kT + ((size_t)(j * 8 + b) * 1024 + wm0 + nl) * 64 + g16 * 8;

    // QK: two half-passes, each with an explicit 8-deep load window
    f32x4 l4[8];
#pragma unroll
    for (int hh = 0; hh < 2; ++hh) {
      uint4 kf[8];
#pragma unroll
      for (int tt = 0; tt < 4; ++tt) {
        const int off = (hh * 4 + tt) * 1024;
        kf[2 * tt]     = *reinterpret_cast<const uint4*>(kp + off);
        kf[2 * tt + 1] = *reinterpret_cast<const uint4*>(kp + off + 32);
      }
#pragma unroll
      for (int tt = 0; tt < 4; ++tt) {
        f32x4 a = f32x4{0.f, 0.f, 0.f, 0.f};
        a = mfmah(bch8(kf[2 * tt]), qh[0], a);
        a = mfmah(bch8(kf[2 * tt + 1]), qh[1], a);
        l4[hh * 4 + tt] = a;
      }
    }

    // stats: per-n max over this wave's 128 m (4-lane group), raw sum (wave)
    float pm = -3.4e38f, es = 0.f;
#pragma unroll
    for (int tt = 0; tt < 8; ++tt) {
#pragma unroll
      for (int r = 0; r < 4; ++r) { pm = fmaxf(pm, l4[tt][r]); es += l4[tt][r]; }
    }
    pm = fmaxf(pm, __shfl_xor(pm, 16, 64));
    pm = fmaxf(pm, __shfl_xor(pm, 32, 64));
    es = wred_sum(es);
    if (lane < 16) redmx[wv * 16 + lane] = pm;
    if (lane == 0) redes[wv] = es;
    __syncthreads();   // sync1: mx ready
    float mx = redmx[nl];
#pragma unroll
    for (int w = 1; w < 8; ++w) mx = fmaxf(mx, redmx[w * 16 + nl]);
    if (t == 0) {
      float s = 0.f;
#pragma unroll
      for (int w = 0; w < 8; ++w) s += redes[w];
      atomicAdd(esum_pam + i * 3 + j, s);
    }

    // exp, per-wave den partials
    float ps = 0.f;
#pragma unroll
    for (int tt = 0; tt < 8; ++tt) {
#pragma unroll
      for (int r = 0; r < 4; ++r) {
        l4[tt][r] = __expf(l4[tt][r] - mx);
        ps += l4[tt][r];
      }
    }
    ps += __shfl_xor(ps, 16, 64);
    ps += __shfl_xor(ps, 32, 64);
    if (lane < 16) redse[wv * 16 + lane] = ps;
    __syncthreads();   // sync2: den ready
    float den = redse[nl];
#pragma unroll
    for (int w = 1; w < 8; ++w) den += redse[w * 16 + nl];
    const float rs = 1.f / den;

    // accumulate P_j/den into Plds (thread-owned cells, fp16 RMW)
#pragma unroll
    for (int tt = 0; tt < 8; ++tt) {
      const int m = wm0 + tt * 16 + g16 * 4;
      unsigned short* pp = &Plds[nl * 1024 + (m ^ (nl * 8))];
      float p0 = l4[tt][0] * rs, p1 = l4[tt][1] * rs;
      float p2 = l4[tt][2] * rs, p3 = l4[tt][3] * rs;
      if (j > 0) {
        const uint2 old = *reinterpret_cast<const uint2*>(pp);
        p0 += h2f((unsigned short)(old.x & 0xffffu));
        p1 += h2f((unsigned short)(old.x >> 16));
        p2 += h2f((unsigned short)(old.y & 0xffffu));
        p3 += h2f((unsigned short)(old.y >> 16));
      }
      uint2 w2; w2.x = pkh(p0, p1); w2.y = pkh(p2, p3);
      *reinterpret_cast<uint2*>(pp) = w2;
    }
  }

  __syncthreads();   // Psum complete

  // Single PV pass: wave covers c-tile ct, m in [mh*512, mh*512+512),
  // explicit 8-deep V load windows.
  const unsigned short* vg = vh + ibo + (size_t)(ct * 16 + nl) * 1024 + mh * 512 + g16 * 8;
  f32x4 oa = f32x4{0.f, 0.f, 0.f, 0.f};
#pragma unroll
  for (int hh = 0; hh < 2; ++hh) {
    uint4 vf[8];
#pragma unroll
    for (int u = 0; u < 8; ++u)
      vf[u] = *reinterpret_cast<const uint4*>(vg + (hh * 8 + u) * 32);
#pragma unroll
    for (int u = 0; u < 8; ++u) {
      const int ml = mh * 512 + (hh * 8 + u) * 32 + g16 * 8;
      const uint4 pf = *reinterpret_cast<const uint4*>(&Plds[nl * 1024 + (ml ^ (nl * 8))]);
      oa = mfmah(bch8(vf[u]), bch8(pf), oa);
    }
  }

  // combine m-halves through LDS (osum aliases qlds), fuse with out_cam
  if (mh == 0) {
#pragma unroll
    for (int r = 0; r < 4; ++r)
      osum[(ct * 16 + g16 * 4 + r) * 16 + nl] = oa[r];
  }
  __syncthreads();
  if (mh == 1) {
    const float* og = ocam + ibo;
    float* outg = tgts + (size_t)(2 * i * 8 + b) * PLANE;
#pragma unroll
    for (int r = 0; r < 4; ++r) {
      const int c = ct * 16 + g16 * 4 + r;
      const int idx = c * N_ + n0 + nl;
      outg[idx] = 0.5f * (oa[r] + osum[c * 16 + nl] + og[idx]);
    }
  }
}

// ---------------------------------------------------------------------------
// alpha[i][j] = 0.5*(softmax_j(mean e_pam) + softmax_j(mean e_cam))
// ---------------------------------------------------------------------------
__global__ void alpha_kernel(const float* __restrict__ esum, float* __restrict__ alpha)
{
  const int t = threadIdx.x;
  if (t >= 9) return;
  const int i = t / 3, j = t % 3;
  float p[3], c[3];
#pragma unroll
  for (int jj = 0; jj < 3; ++jj) {
    p[jj] = esum[i * 3 + jj] * (1.0f / 8388608.0f);
    c[jj] = esum[9 + i * 3 + jj] * (1.0f / 32768.0f);
  }
  const float mp = fmaxf(p[0], fmaxf(p[1], p[2]));
  const float mc = fmaxf(c[0], fmaxf(c[1], c[2]));
  float sp = 0.f, sc = 0.f;
#pragma unroll
  for (int jj = 0; jj < 3; ++jj) { sp += __expf(p[jj] - mp); sc += __expf(c[jj] - mc); }
  alpha[t] = 0.5f * (__expf(p[j] - mp) / sp + __expf(c[j] - mc) / sc);
}

// ---------------------------------------------------------------------------
extern "C" void kernel_launch(void* const* d_in, const int* in_sizes, int n_in,
                              void* d_out, int out_size, void* d_ws, size_t ws_size,
                              hipStream_t stream)
{
  const float* src0 = (const float*)d_in[0];
  const float* src1 = (const float*)d_in[1];
  const float* src2 = (const float*)d_in[2];
  const float* tgt0 = (const float*)d_in[3];
  const float* tgt1 = (const float*)d_in[4];
  const float* tgt2 = (const float*)d_in[5];
  const float* fs0_w = (const float*)d_in[6];  const float* fs0_b = (const float*)d_in[7];
  const float* fs1_w = (const float*)d_in[8];  const float* fs1_b = (const float*)d_in[9];
  const float* fs2_w = (const float*)d_in[10]; const float* fs2_b = (const float*)d_in[11];
  const float* ft0_w = (const float*)d_in[12]; const float* ft0_b = (const float*)d_in[13];
  const float* ft1_w = (const float*)d_in[14]; const float* ft1_b = (const float*)d_in[15];
  const float* ft2_w = (const float*)d_in[16]; const float* ft2_b = (const float*)d_in[17];
  const float* pq_w = (const float*)d_in[18];  const float* pq_b = (const float*)d_in[19];
  const float* pk_w = (const float*)d_in[20];  const float* pk_b = (const float*)d_in[21];
  const float* pv_w = (const float*)d_in[22];  const float* pv_b = (const float*)d_in[23];
  const float* cv_w = (const float*)d_in[24];  const float* cv_b = (const float*)d_in[25];

  float* out = (float*)d_out;
  float* S     = out;                 // srcs region doubles as S storage
  float* alpha = out + SZ;            // 9 floats
  float* tgts  = out + SZ + 9;        // [2L][B][PLANE]

  float* ws   = (float*)d_ws;
  float* T    = ws;
  float* qb   = ws + (size_t)SZ;
  float* kb   = ws + (size_t)2 * SZ;
  float* vb   = ws + (size_t)3 * SZ;
  float* vcb  = ws + (size_t)4 * SZ;
  float* ocam = ws + (size_t)5 * SZ;
  float* ecam = ws + (size_t)6 * SZ;                 // 294912
  float* acam = ws + (size_t)6 * SZ + 294912;        // 98304
  float* esum = ws + (size_t)6 * SZ + 393216;        // 18 (pam 9, cam 9)

  // fp16 buffers appended after the fp32 region
  unsigned short* kT = (unsigned short*)(ws + (size_t)6 * SZ + 393216 + 256);
  unsigned short* vh = kT + (size_t)24 * PLANE;
  unsigned short* wh = vh + (size_t)24 * PLANE;      // 98304 ushorts
  unsigned short* w9s = wh + 98304;                  // 73728 ushorts
  unsigned short* w9t = w9s + 73728;

  // Overlays in qb..vcb (each consumed before the next producer writes):
  unsigned short* inTs = (unsigned short*)qb;        // 8*4096*128
  unsigned short* inTt = inTs + 4194304;
  unsigned short* Xs1 = (unsigned short*)qb;         // 8x1024x256
  unsigned short* Xs2 = Xs1 + 2097152;               // 8x1024x512
  unsigned short* Xt1 = Xs1 + 6291456;               // 8x1024x256
  unsigned short* Xt2 = Xs1 + 8388608;               // 8x1024x512

  hipMemsetAsync(esum, 0, 18 * sizeof(float), stream);

  // conv0 via MFMA: channels-last fp16 inputs + fp16 tap weights
  w9conv_kernel<<<576, 256, 0, stream>>>(fs0_w, ft0_w, w9s, w9t);
  xprep_kernel<<<dim3(8, 2, 64), 256, 0, stream>>>(src0, inTs, 128, 4096);
  xprep_kernel<<<dim3(8, 2, 64), 256, 0, stream>>>(tgt0, inTt, 128, 4096);
  conv0_mfma_kernel<<<dim3(32, 8, 2), 256, 0, stream>>>(
      inTs, inTt, w9s, w9t, fs0_b, ft0_b, S, T, tgts + (size_t)1 * BPL);

  // fp16 fit GEMMs (overwrite the inT overlay with Xh)
  xprep_kernel<<<dim3(8, 4, 16), 256, 0, stream>>>(src1, Xs1, 256, 1024);
  xprep_kernel<<<dim3(8, 8, 16), 256, 0, stream>>>(src2, Xs2, 512, 1024);
  xprep_kernel<<<dim3(8, 4, 16), 256, 0, stream>>>(tgt1, Xt1, 256, 1024);
  xprep_kernel<<<dim3(8, 8, 16), 256, 0, stream>>>(tgt2, Xt2, 512, 1024);
  whconv_kernel<<<192, 256, 0, stream>>>(fs1_w, fs2_w, ft1_w, ft2_w, wh);
  gemmh_kernel<<<dim3(16, 16), 256, 0, stream>>>(
      Xs1, Xt1, wh, wh + 49152, fs1_b, ft1_b,
      S + BPL, T + BPL, tgts + (size_t)3 * BPL, 256);
  gemmh_kernel<<<dim3(16, 16), 256, 0, stream>>>(
      Xs2, Xt2, wh + 16384, wh + 65536, fs2_b, ft2_b,
      S + 2 * BPL, T + 2 * BPL, tgts + (size_t)5 * BPL, 512);

  // All 4 projections in one launch (writes qb..vcb, overwriting the overlay)
  proj_kernel<<<dim3(24, 16, 4), 256, 0, stream>>>(
      T, S, pq_w, pk_w, pv_w, cv_w, pq_b, pk_b, pv_b, cv_b, qb);

  // Pack k (transposed fp16) and v (fp16) for the MFMA attention
  kprep_kernel<<<dim3(24, 4), 256, 0, stream>>>(kb, vb, kT, vh);

  // CAM
  ecam_kernel<<<72, 256, 0, stream>>>(T, S, ecam, esum + 9);
  acam_kernel<<<24, 256, 0, stream>>>(ecam, acam);
  gemm64_kernel<<<dim3(24, 16), 256, 0, stream>>>(acam, 4096, 1, vcb, PLANE, ocam, PLANE,
                                                  nullptr, 0, 64);

  // PAM + fuse (writes tgts even slots = 0.5*(out_pam + out_cam))
  pam_mfma_kernel<<<1536, 512, 0, stream>>>(qb, kT, vh, ocam, tgts, esum);

  alpha_kernel<<<1, 64, 0, stream>>>(esum, alpha);
}

// Round 15
// 296.777 us; speedup vs baseline: 1.4021x; 1.1045x over previous
//
#include <hip/hip_runtime.h>

// Problem constants
static constexpr int L_ = 3, B_ = 8, C_ = 64, N_ = 1024;
static constexpr int PLANE = C_ * N_;       // 65536
static constexpr int SZ    = L_ * B_ * PLANE; // 1572864
static constexpr int BPL   = B_ * PLANE;    // 524288

#define DI __device__ __forceinline__

typedef _Float16 h8 __attribute__((ext_vector_type(8)));   // 8 fp16 (MFMA A/B frag)
typedef __attribute__((ext_vector_type(4))) float f32x4;   // MFMA C/D frag
typedef unsigned int uint32;

DI float wred_sum(float v) {
#pragma unroll
  for (int m = 1; m < 64; m <<= 1) v += __shfl_xor(v, m, 64);
  return v;
}

DI unsigned short f2h(float f) {
  return __builtin_bit_cast(unsigned short, (_Float16)f);
}
DI float h2f(unsigned short h) {
  return (float)__builtin_bit_cast(_Float16, h);
}
DI uint32 pkh(float a, float b) {
  return (uint32)f2h(a) | ((uint32)f2h(b) << 16);
}
DI h8 bch8(uint4 v) { return __builtin_bit_cast(h8, v); }

DI f32x4 mfmah(h8 a, h8 b, f32x4 c) {
  return __builtin_amdgcn_mfma_f32_16x16x32_f16(a, b, c, 0, 0, 0);
}

// ---------------------------------------------------------------------------
// xprep body: transpose+convert one 64x64 tile of in[K][N] fp32 -> out[N][K]
// fp16. ing/og pre-offset to the (g,kc,nc) tile.
// ---------------------------------------------------------------------------
DI void xprep_body(const float* __restrict__ ing, unsigned short* __restrict__ og,
                   int K, int N, int t, float tl[64][65])
{
#pragma unroll 4
  for (int r = 0; r < 16; ++r) {
    const int kk = r * 4 + (t >> 6);
    tl[kk][t & 63] = ing[(size_t)kk * N + (t & 63)];
  }
  __syncthreads();
  const int mm = t >> 2, kseg = (t & 3) * 16;
  uint32 hw[8];
#pragma unroll
  for (int ii = 0; ii < 8; ++ii)
    hw[ii] = pkh(tl[kseg + 2 * ii][mm], tl[kseg + 2 * ii + 1][mm]);
  unsigned short* o = og + (size_t)mm * K + kseg;
  uint4 h0; h0.x = hw[0]; h0.y = hw[1]; h0.z = hw[2]; h0.w = hw[3];
  uint4 h1; h1.x = hw[4]; h1.y = hw[5]; h1.z = hw[6]; h1.w = hw[7];
  *reinterpret_cast<uint4*>(o)     = h0;
  *reinterpret_cast<uint4*>(o + 8) = h1;
}

// conv inputs: grid (16, 2, 64): x = tsel*8 + g; K=128, N=4096.
__global__ __launch_bounds__(256) void xprep_conv_kernel(
    const float* __restrict__ in_s, const float* __restrict__ in_t,
    unsigned short* __restrict__ o_s, unsigned short* __restrict__ o_t)
{
  __shared__ float tl[64][65];
  const int g = blockIdx.x & 7, ts = blockIdx.x >> 3;
  const int kc = blockIdx.y, nc = blockIdx.z;
  const float* in = ts ? in_t : in_s;
  unsigned short* out = ts ? o_t : o_s;
  const float* ing = in + (size_t)g * 128 * 4096 + (size_t)(kc * 64) * 4096 + nc * 64;
  unsigned short* og = out + ((size_t)g * 4096 + nc * 64) * 128 + kc * 64;
  xprep_body(ing, og, 128, 4096, threadIdx.x, tl);
}

// fit inputs, all 4 tensors in one launch: grid (32, 8, 16): x = ts*8 + g.
// K = 256 for ts 0,2; 512 for ts 1,3. Uniform early-exit when kc >= K/64.
__global__ __launch_bounds__(256) void xprep_fit_kernel(
    const float* __restrict__ s1, const float* __restrict__ s2,
    const float* __restrict__ t1, const float* __restrict__ t2,
    unsigned short* __restrict__ x1, unsigned short* __restrict__ x2,
    unsigned short* __restrict__ x3, unsigned short* __restrict__ x4)
{
  __shared__ float tl[64][65];
  const int g = blockIdx.x & 7, ts = blockIdx.x >> 3;
  const int K = (ts & 1) ? 512 : 256;
  const int kc = blockIdx.y, nc = blockIdx.z;
  if (kc >= (K >> 6)) return;
  const float* in = (ts == 0) ? s1 : (ts == 1) ? s2 : (ts == 2) ? t1 : t2;
  unsigned short* out = (ts == 0) ? x1 : (ts == 1) ? x2 : (ts == 2) ? x3 : x4;
  const float* ing = in + (size_t)g * K * 1024 + (size_t)(kc * 64) * 1024 + nc * 64;
  unsigned short* og = out + ((size_t)g * 1024 + nc * 64) * K + kc * 64;
  xprep_body(ing, og, K, 1024, threadIdx.x, tl);
}

// ---------------------------------------------------------------------------
// w9conv: conv weights w[co][ci][k9] fp32 -> w9[k9][co][ci] fp16 (both s,t).
// grid 576.
// ---------------------------------------------------------------------------
__global__ __launch_bounds__(256) void w9conv_kernel(
    const float* __restrict__ w_s, const float* __restrict__ w_t,
    unsigned short* __restrict__ w9_s, unsigned short* __restrict__ w9_t)
{
  const int e = blockIdx.x * 256 + threadIdx.x;  // 0..147455
  const float* w = (e < 73728) ? w_s : w_t;
  unsigned short* o = (e < 73728) ? w9_s : w9_t;
  const int le = (e < 73728) ? e : e - 73728;
  const int ci = le & 127;
  const int q = le >> 7;
  const int co = q & 63;
  const int k9 = q >> 6;
  o[le] = f2h(w[(co * 128 + ci) * 9 + k9]);
}

// ---------------------------------------------------------------------------
// conv0 via MFMA: 3x3 s2 p1, 128->64, channels-last fp16 inT[b][pix][ci],
// w9[tap][co][ci]. grid (32 out-rows, 8 b, 2 st), 256 thr = 4 waves.
// ---------------------------------------------------------------------------
__global__ __launch_bounds__(256) void conv0_mfma_kernel(
    const unsigned short* __restrict__ inT_s, const unsigned short* __restrict__ inT_t,
    const unsigned short* __restrict__ w9_s, const unsigned short* __restrict__ w9_t,
    const float* __restrict__ b_s, const float* __restrict__ b_t,
    float* __restrict__ Sout, float* __restrict__ Tout, float* __restrict__ tdup)
{
  const int yr = blockIdx.x;          // output row 0..31
  const int b  = blockIdx.y;
  const int st = blockIdx.z;
  const unsigned short* inT = st ? inT_t : inT_s;
  const unsigned short* w9  = st ? w9_t  : w9_s;
  const float* bias = st ? b_t : b_s;
  float* outA = st ? Tout : Sout;

  const int t = threadIdx.x, lane = t & 63;
  const int ct = t >> 6;              // co-tile
  const int nl = lane & 15, g16 = lane >> 4;
  const unsigned short* inb = inT + (size_t)b * (4096 * 128);
  const unsigned short* wbase = w9 + (size_t)(ct * 16 + nl) * 128;

  f32x4 acc0 = f32x4{0.f, 0.f, 0.f, 0.f};
  f32x4 acc1 = f32x4{0.f, 0.f, 0.f, 0.f};
  const uint4 zz = uint4{0u, 0u, 0u, 0u};

#pragma unroll 1
  for (int tap = 0; tap < 9; ++tap) {
    const int ky = tap / 3, kx = tap - 3 * (tap / 3);
    const int py = 2 * yr - 1 + ky;                 // [-1, 63]
    const int px0 = 2 * nl - 1 + kx;                // nt=0: x = nl
    const int px1 = px0 + 32;                       // nt=1: x = 16+nl (>=31)
    const bool v0 = (py >= 0) && (px0 >= 0);
    const bool v1 = (py >= 0);
    const unsigned short* prow = inb + (ptrdiff_t)py * (64 * 128);
#pragma unroll
    for (int ks = 0; ks < 4; ++ks) {
      const h8 a = bch8(*reinterpret_cast<const uint4*>(
          wbase + tap * 8192 + ks * 32 + g16 * 8));
      const uint4 bv0 = v0 ? *reinterpret_cast<const uint4*>(
                                 prow + px0 * 128 + ks * 32 + g16 * 8) : zz;
      const uint4 bv1 = v1 ? *reinterpret_cast<const uint4*>(
                                 prow + px1 * 128 + ks * 32 + g16 * 8) : zz;
      acc0 = mfmah(a, bch8(bv0), acc0);
      acc1 = mfmah(a, bch8(bv1), acc1);
    }
  }

  const int yb = yr * 32;
#pragma unroll
  for (int r = 0; r < 4; ++r) {
    const int co = ct * 16 + g16 * 4 + r;
    const float bv = bias[co];
    const int idx = (b * 64 + co) * 1024 + yb + nl;
    const float o0 = acc0[r] + bv;
    const float o1 = acc1[r] + bv;
    outA[idx] = o0; outA[idx + 16] = o1;
    if (st) { tdup[idx] = o0; tdup[idx + 16] = o1; }
  }
}

// ---------------------------------------------------------------------------
// Generic fp32 out[g][64][1024] = W[g/wdiv][64][K] @ X[g][K][1024] + bias
// (kept for attn_cam @ vc)
// ---------------------------------------------------------------------------
__global__ __launch_bounds__(256) void gemm64_kernel(
    const float* __restrict__ W, int wstride, int wdiv,
    const float* __restrict__ X, int xstride,
    float* __restrict__ out, int ostride,
    const float* __restrict__ bias, int bstride,
    int K)
{
  const int g  = blockIdx.x;
  const int n0 = blockIdx.y * 64;
  const float* Wg = W + (size_t)(g / wdiv) * wstride;
  const float* Xg = X + (size_t)g * xstride;
  const int t = threadIdx.x;
  __shared__ float Xs[32][64];
  __shared__ float Ws[32][64];
  const int tn = t & 15, cgp = t >> 4;
  const int n4 = tn * 4, co4 = cgp * 4;
  float acc[4][4] = {};

  for (int k0 = 0; k0 < K; k0 += 32) {
    {
      const int kk = t >> 4;
      const int nn = (t & 15) * 4;
      *reinterpret_cast<float4*>(&Xs[kk][nn]) =
          *reinterpret_cast<const float4*>(Xg + (size_t)(k0 + kk) * N_ + n0 + nn);
      *reinterpret_cast<float4*>(&Xs[kk + 16][nn]) =
          *reinterpret_cast<const float4*>(Xg + (size_t)(k0 + kk + 16) * N_ + n0 + nn);
    }
    {
      const int co = t & 63, q4 = t >> 6;
      const float* wp = Wg + (size_t)co * K + k0 + q4 * 8;
      const float4 a = *reinterpret_cast<const float4*>(wp);
      const float4 c = *reinterpret_cast<const float4*>(wp + 4);
      const int kb = q4 * 8;
      Ws[kb + 0][co] = a.x; Ws[kb + 1][co] = a.y; Ws[kb + 2][co] = a.z; Ws[kb + 3][co] = a.w;
      Ws[kb + 4][co] = c.x; Ws[kb + 5][co] = c.y; Ws[kb + 6][co] = c.z; Ws[kb + 7][co] = c.w;
    }
    __syncthreads();
#pragma unroll
    for (int kk = 0; kk < 32; ++kk) {
      const float4 xv = *reinterpret_cast<const float4*>(&Xs[kk][n4]);
      const float4 wv = *reinterpret_cast<const float4*>(&Ws[kk][co4]);
      const float xa[4] = {xv.x, xv.y, xv.z, xv.w};
      const float wa[4] = {wv.x, wv.y, wv.z, wv.w};
#pragma unroll
      for (int a = 0; a < 4; ++a)
#pragma unroll
        for (int b2 = 0; b2 < 4; ++b2)
          acc[a][b2] = fmaf(wa[a], xa[b2], acc[a][b2]);
    }
    __syncthreads();
  }

  float bv[4] = {0.f, 0.f, 0.f, 0.f};
  if (bias) {
    const float* bg = bias + (size_t)(g / wdiv) * bstride;
    bv[0] = bg[co4]; bv[1] = bg[co4 + 1]; bv[2] = bg[co4 + 2]; bv[3] = bg[co4 + 3];
  }
#pragma unroll
  for (int ii = 0; ii < 4; ++ii) {
    float4 o4;
    o4.x = acc[ii][0] + bv[ii]; o4.y = acc[ii][1] + bv[ii];
    o4.z = acc[ii][2] + bv[ii]; o4.w = acc[ii][3] + bv[ii];
    *reinterpret_cast<float4*>(out + (size_t)g * ostride + (co4 + ii) * N_ + n0 + n4) = o4;
  }
}

// ---------------------------------------------------------------------------
// proj: all 4 projections in ONE launch, emitting pam-ready fp16 directly:
// z=0 -> qT[g][n][c] fp16 (transposed); z=1 -> kT[g][n][c] fp16;
// z=2 -> vh[g][c][n] fp16; z=3 -> vcb fp32 (consumed by gemm64).
// grid (24, 16, 4). Kills the separate kprep pass + fp32 q/k/v round-trips.
// ---------------------------------------------------------------------------
__global__ __launch_bounds__(256) void proj_kernel(
    const float* __restrict__ Tm, const float* __restrict__ Sm,
    const float* __restrict__ wq, const float* __restrict__ wk,
    const float* __restrict__ wv2, const float* __restrict__ wc,
    const float* __restrict__ bq, const float* __restrict__ bk,
    const float* __restrict__ bv2, const float* __restrict__ bc,
    unsigned short* __restrict__ qT, unsigned short* __restrict__ kT,
    unsigned short* __restrict__ vh, float* __restrict__ vcb)
{
  const int g  = blockIdx.x;          // i*8+b
  const int n0 = blockIdx.y * 64;
  const int z  = blockIdx.z;          // 0=q 1=k 2=v 3=vc
  const float* W  = (z == 0) ? wq : (z == 1) ? wk : (z == 2) ? wv2 : wc;
  const float* bi = (z == 0) ? bq : (z == 1) ? bk : (z == 2) ? bv2 : bc;
  const float* Xg = ((z == 1) ? Sm : Tm) + (size_t)g * PLANE;
  const float* Wg = W + (g >> 3) * 4096;
  const float* bg = bi + (g >> 3) * 64;

  const int t = threadIdx.x;
  __shared__ float Xs[32][64];
  __shared__ float Ws[32][64];
  const int tn = t & 15, cgp = t >> 4;
  const int n4 = tn * 4, co4 = cgp * 4;
  float acc[4][4] = {};

#pragma unroll 1
  for (int k0 = 0; k0 < 64; k0 += 32) {
    {
      const int kk = t >> 4;
      const int nn = (t & 15) * 4;
      *reinterpret_cast<float4*>(&Xs[kk][nn]) =
          *reinterpret_cast<const float4*>(Xg + (size_t)(k0 + kk) * N_ + n0 + nn);
      *reinterpret_cast<float4*>(&Xs[kk + 16][nn]) =
          *reinterpret_cast<const float4*>(Xg + (size_t)(k0 + kk + 16) * N_ + n0 + nn);
    }
    {
      const int co = t & 63, q4 = t >> 6;
      const float* wp = Wg + (size_t)co * 64 + k0 + q4 * 8;
      const float4 a = *reinterpret_cast<const float4*>(wp);
      const float4 c = *reinterpret_cast<const float4*>(wp + 4);
      const int kb = q4 * 8;
      Ws[kb + 0][co] = a.x; Ws[kb + 1][co] = a.y; Ws[kb + 2][co] = a.z; Ws[kb + 3][co] = a.w;
      Ws[kb + 4][co] = c.x; Ws[kb + 5][co] = c.y; Ws[kb + 6][co] = c.z; Ws[kb + 7][co] = c.w;
    }
    __syncthreads();
#pragma unroll
    for (int kk = 0; kk < 32; ++kk) {
      const float4 xv = *reinterpret_cast<const float4*>(&Xs[kk][n4]);
      const float4 wv = *reinterpret_cast<const float4*>(&Ws[kk][co4]);
      const float xa[4] = {xv.x, xv.y, xv.z, xv.w};
      const float wa[4] = {wv.x, wv.y, wv.z, wv.w};
#pragma unroll
      for (int a = 0; a < 4; ++a)
#pragma unroll
        for (int b2 = 0; b2 < 4; ++b2)
          acc[a][b2] = fmaf(wa[a], xa[b2], acc[a][b2]);
    }
    __syncthreads();
  }

  float bvv[4];
#pragma unroll
  for (int ii = 0; ii < 4; ++ii) bvv[ii] = bg[co4 + ii];

  if (z <= 1) {
    // transposed fp16 [g][n][c]
    unsigned short* out = (z == 0 ? qT : kT);
#pragma unroll
    for (int jj = 0; jj < 4; ++jj) {
      const size_t base = ((size_t)g * 1024 + n0 + n4 + jj) * 64 + co4;
      uint2 w2;
      w2.x = pkh(acc[0][jj] + bvv[0], acc[1][jj] + bvv[1]);
      w2.y = pkh(acc[2][jj] + bvv[2], acc[3][jj] + bvv[3]);
      *reinterpret_cast<uint2*>(out + base) = w2;
    }
  } else if (z == 2) {
    // linear fp16 [g][c][n]
#pragma unroll
    for (int ii = 0; ii < 4; ++ii) {
      const size_t base = ((size_t)g * 64 + co4 + ii) * 1024 + n0 + n4;
      uint2 w2;
      w2.x = pkh(acc[ii][0] + bvv[ii], acc[ii][1] + bvv[ii]);
      w2.y = pkh(acc[ii][2] + bvv[ii], acc[ii][3] + bvv[ii]);
      *reinterpret_cast<uint2*>(vh + base) = w2;
    }
  } else {
    float* out = vcb + (size_t)g * PLANE;
#pragma unroll
    for (int ii = 0; ii < 4; ++ii) {
      float4 o4;
      o4.x = acc[ii][0] + bvv[ii]; o4.y = acc[ii][1] + bvv[ii];
      o4.z = acc[ii][2] + bvv[ii]; o4.w = acc[ii][3] + bvv[ii];
      *reinterpret_cast<float4*>(out + (co4 + ii) * N_ + n0 + n4) = o4;
    }
  }
}

// ---------------------------------------------------------------------------
// whconv: fit-GEMM weights to fp16: wh1s@0, wh2s@16384, wh1t@49152, wh2t@65536
// ---------------------------------------------------------------------------
__global__ __launch_bounds__(256) void whconv_kernel(
    const float* __restrict__ w1s, const float* __restrict__ w2s,
    const float* __restrict__ w1t, const float* __restrict__ w2t,
    unsigned short* __restrict__ wh)
{
  const int p = blockIdx.x * 256 + threadIdx.x;  // pair index 0..49151
  const float* in; int local; unsigned short* out;
  if (p < 8192)       { in = w1s; local = p;         out = wh; }
  else if (p < 24576) { in = w2s; local = p - 8192;  out = wh + 16384; }
  else if (p < 32768) { in = w1t; local = p - 24576; out = wh + 49152; }
  else                { in = w2t; local = p - 32768; out = wh + 65536; }
  const float2 v = *reinterpret_cast<const float2*>(in + 2 * local);
  *reinterpret_cast<uint32*>(out + 2 * local) = pkh(v.x, v.y);
}

// ---------------------------------------------------------------------------
// gemmh: fp16 MFMA fit-GEMM. out[g][64co][1024n] = W[64][K] @ Xh[n][K].
// grid (16, 16); g<8 = src, g>=8 = tgt (+dual write).
// ---------------------------------------------------------------------------
__global__ __launch_bounds__(256) void gemmh_kernel(
    const unsigned short* __restrict__ Xa, const unsigned short* __restrict__ Xb,
    const unsigned short* __restrict__ Wa, const unsigned short* __restrict__ Wb,
    const float* __restrict__ ba, const float* __restrict__ bb,
    float* __restrict__ oa, float* __restrict__ ob, float* __restrict__ o2b,
    int K)
{
  const int g = blockIdx.x;
  const bool isb = g >= 8;
  const int gl = g & 7;
  const unsigned short* X = (isb ? Xb : Xa) + (size_t)gl * 1024 * K;
  const unsigned short* W = isb ? Wb : Wa;
  const float* bias = isb ? bb : ba;
  float* out = (isb ? ob : oa) + (size_t)gl * PLANE;
  float* out2 = isb ? o2b + (size_t)gl * PLANE : nullptr;

  const int t = threadIdx.x, lane = t & 63, wv = t >> 6;
  const int nl = lane & 15, g16 = lane >> 4;
  const int n0w = blockIdx.y * 64 + wv * 16;

  const unsigned short* xp = X + (size_t)(n0w + nl) * K + g16 * 8;
  const unsigned short* wp = W + (size_t)nl * K + g16 * 8;

  f32x4 acc[4];
#pragma unroll
  for (int ct = 0; ct < 4; ++ct) acc[ct] = f32x4{0.f, 0.f, 0.f, 0.f};

#pragma unroll 4
  for (int kk = 0; kk < K; kk += 32) {
    const h8 a = bch8(*reinterpret_cast<const uint4*>(xp + kk));
#pragma unroll
    for (int ct = 0; ct < 4; ++ct) {
      const h8 bfr = bch8(*reinterpret_cast<const uint4*>(wp + (size_t)ct * 16 * K + kk));
      acc[ct] = mfmah(a, bfr, acc[ct]);
    }
  }

#pragma unroll
  for (int ct = 0; ct < 4; ++ct) {
    const int co = ct * 16 + nl;
    const float bv = bias[co];
    float4 o4;
    o4.x = acc[ct][0] + bv; o4.y = acc[ct][1] + bv;
    o4.z = acc[ct][2] + bv; o4.w = acc[ct][3] + bv;
    const int idx = co * N_ + n0w + g16 * 4;
    *reinterpret_cast<float4*>(out + idx) = o4;
    if (out2) {
      out2[idx] = o4.x; out2[idx + 1] = o4.y;
      out2[idx + 2] = o4.z; out2[idx + 3] = o4.w;
    }
  }
}

// ---------------------------------------------------------------------------
// e_cam partials: grid (72, 4) - each block covers 256 n, atomicAdd into ecam
// (zeroed by memset). 4x the blocks of the old 72-block version (was 0.28
// blocks/CU = pure serial latency).
// ---------------------------------------------------------------------------
__global__ __launch_bounds__(256) void ecam_kernel(
    const float* __restrict__ T, const float* __restrict__ S,
    float* __restrict__ ecam, float* __restrict__ esum_cam)
{
  const int bx = blockIdx.x;
  const int b = bx & 7;
  const int j = (bx >> 3) % 3;
  const int i = bx / 24;
  const int ych = blockIdx.y;
  const float* Tg = T + (size_t)(i * 8 + b) * PLANE;
  const float* Sg = S + (size_t)(j * 8 + b) * PLANE;
  const int t = threadIdx.x;
  __shared__ float Ts[64 * 68];
  __shared__ float Ss[64 * 68];
  __shared__ float rs[4];
  float acc[4][4] = {};
  const int c0 = (t & 15) * 4, d0 = (t >> 4) * 4;

  for (int nb = ych * 256; nb < ych * 256 + 256; nb += 64) {
    __syncthreads();
    {
      const int nn = t & 63, rb = t >> 6;
#pragma unroll
      for (int r = 0; r < 16; ++r) {
        const int row = rb * 16 + r;
        Ts[nn * 68 + row] = Tg[row * N_ + nb + nn];
        Ss[nn * 68 + row] = Sg[row * N_ + nb + nn];
      }
    }
    __syncthreads();
#pragma unroll 8
    for (int nn = 0; nn < 64; ++nn) {
      const float4 tv = *reinterpret_cast<const float4*>(&Ts[nn * 68 + c0]);
      const float4 sv = *reinterpret_cast<const float4*>(&Ss[nn * 68 + d0]);
      const float ta[4] = {tv.x, tv.y, tv.z, tv.w};
      const float sa[4] = {sv.x, sv.y, sv.z, sv.w};
#pragma unroll
      for (int ci = 0; ci < 4; ++ci)
#pragma unroll
        for (int di = 0; di < 4; ++di)
          acc[ci][di] = fmaf(ta[ci], sa[di], acc[ci][di]);
    }
  }
  float s = 0.f;
#pragma unroll
  for (int ci = 0; ci < 4; ++ci)
#pragma unroll
    for (int di = 0; di < 4; ++di) s += acc[ci][di];
  s = wred_sum(s);
  if ((t & 63) == 0) rs[t >> 6] = s;
  __syncthreads();
  if (t == 0) atomicAdd(esum_cam + i * 3 + j, rs[0] + rs[1] + rs[2] + rs[3]);

  float* eo = ecam + (size_t)((i * 3 + j) * 8 + b) * 4096;
#pragma unroll
  for (int ci = 0; ci < 4; ++ci)
#pragma unroll
    for (int di = 0; di < 4; ++di)
      atomicAdd(eo + (c0 + ci) * 64 + d0 + di, acc[ci][di]);
}

// ---------------------------------------------------------------------------
// attn_cam[i,b][c][d] = sum_j softmax_d(e_cam[i,j,b,c,:])[d]     grid 24
// ---------------------------------------------------------------------------
__global__ __launch_bounds__(256) void acam_kernel(
    const float* __restrict__ ecam, float* __restrict__ acam)
{
  const int bx = blockIdx.x;
  const int b = bx & 7, i = bx >> 3;
  const int t = threadIdx.x;
  const int c = t >> 2, seg = t & 3;
  float acc[16] = {};
#pragma unroll
  for (int j = 0; j < 3; ++j) {
    const float* e = ecam + (size_t)((i * 3 + j) * 8 + b) * 4096 + c * 64 + seg * 16;
    float ev[16];
#pragma unroll
    for (int r = 0; r < 4; ++r) {
      const float4 v4 = *reinterpret_cast<const float4*>(e + r * 4);
      ev[4 * r] = v4.x; ev[4 * r + 1] = v4.y; ev[4 * r + 2] = v4.z; ev[4 * r + 3] = v4.w;
    }
    float mx = ev[0];
#pragma unroll
    for (int r = 1; r < 16; ++r) mx = fmaxf(mx, ev[r]);
    mx = fmaxf(mx, __shfl_xor(mx, 1, 4));
    mx = fmaxf(mx, __shfl_xor(mx, 2, 4));
    float pv[16], ss = 0.f;
#pragma unroll
    for (int r = 0; r < 16; ++r) { pv[r] = __expf(ev[r] - mx); ss += pv[r]; }
    ss += __shfl_xor(ss, 1, 4);
    ss += __shfl_xor(ss, 2, 4);
    const float rc = 1.f / ss;
#pragma unroll
    for (int r = 0; r < 16; ++r) acc[r] += pv[r] * rc;
  }
  float* ao = acam + (size_t)(i * 8 + b) * 4096 + c * 64 + seg * 16;
#pragma unroll
  for (int r = 0; r < 4; ++r) {
    float4 o4; o4.x = acc[4 * r]; o4.y = acc[4 * r + 1]; o4.z = acc[4 * r + 2]; o4.w = acc[4 * r + 3];
    *reinterpret_cast<float4*>(ao + r * 4) = o4;
  }
}

// ---------------------------------------------------------------------------
// PAM via fp16 MFMA, 8 waves x 128 m, Psum in LDS across j, single PV pass.
// Q loaded directly from qT fp16 (2 contiguous uint4) - no q staging phase.
// grid 1536 = (i, b, qt), 512 threads.
// ---------------------------------------------------------------------------
__global__ __launch_bounds__(512, 4) void pam_mfma_kernel(
    const unsigned short* __restrict__ qT, const unsigned short* __restrict__ kT,
    const unsigned short* __restrict__ vh,
    const float* __restrict__ ocam, float* __restrict__ tgts, float* __restrict__ esum_pam)
{
  const int bx = blockIdx.x;
  const int qt = bx & 63;
  const int b  = (bx >> 6) & 7;
  const int i  = bx >> 9;
  const int n0 = qt * 16;
  const int t = threadIdx.x;
  const int lane = t & 63;
  const int wv = t >> 6;             // 0..7
  const int nl = lane & 15;
  const int g16 = lane >> 4;

  __shared__ unsigned short Plds[16 * 1024];  // 32 KB fp16 Psum, [n][m ^ (8n)]
  __shared__ float osum[64 * 16];             // 4 KB m-half combine
  __shared__ float redmx[128];
  __shared__ float redse[128];
  __shared__ float redes[8];

  const size_t ibo = (size_t)(i * 8 + b) * PLANE;
  const size_t gbase = (size_t)(i * 8 + b) * 1024;

  // Q B-fragments: direct contiguous fp16 loads from qT[g][n][c]
  const unsigned short* qp = qT + (gbase + n0 + nl) * 64 + g16 * 8;
  const h8 qh0 = bch8(*reinterpret_cast<const uint4*>(qp));
  const h8 qh1 = bch8(*reinterpret_cast<const uint4*>(qp + 32));

  const int wm0 = wv * 128;
  const int ct = wv & 3;
  const int mh = wv >> 2;

#pragma unroll 1
  for (int j = 0; j < 3; ++j) {
    const unsigned short* kp =
        kT + ((size_t)(j * 8 + b) * 1024 + wm0 + nl) * 64 + g16 * 8;

    // QK: two half-passes, each with an explicit 8-deep load window
    f32x4 l4[8];
#pragma unroll
    for (int hh = 0; hh < 2; ++hh) {
      uint4 kf[8];
#pragma unroll
      for (int tt = 0; tt < 4; ++tt) {
        const int off = (hh * 4 + tt) * 1024;
        kf[2 * tt]     = *reinterpret_cast<const uint4*>(kp + off);
        kf[2 * tt + 1] = *reinterpret_cast<const uint4*>(kp + off + 32);
      }
#pragma unroll
      for (int tt = 0; tt < 4; ++tt) {
        f32x4 a = f32x4{0.f, 0.f, 0.f, 0.f};
        a = mfmah(bch8(kf[2 * tt]), qh0, a);
        a = mfmah(bch8(kf[2 * tt + 1]), qh1, a);
        l4[hh * 4 + tt] = a;
      }
    }

    // stats: per-n max over this wave's 128 m (4-lane group), raw sum (wave)
    float pm = -3.4e38f, es = 0.f;
#pragma unroll
    for (int tt = 0; tt < 8; ++tt) {
#pragma unroll
      for (int r = 0; r < 4; ++r) { pm = fmaxf(pm, l4[tt][r]); es += l4[tt][r]; }
    }
    pm = fmaxf(pm, __shfl_xor(pm, 16, 64));
    pm = fmaxf(pm, __shfl_xor(pm, 32, 64));
    es = wred_sum(es);
    if (lane < 16) redmx[wv * 16 + lane] = pm;
    if (lane == 0) redes[wv] = es;
    __syncthreads();   // sync1: mx ready
    float mx = redmx[nl];
#pragma unroll
    for (int w = 1; w < 8; ++w) mx = fmaxf(mx, redmx[w * 16 + nl]);
    if (t == 0) {
      float s = 0.f;
#pragma unroll
      for (int w = 0; w < 8; ++w) s += redes[w];
      atomicAdd(esum_pam + i * 3 + j, s);
    }

    // exp, per-wave den partials
    float ps = 0.f;
#pragma unroll
    for (int tt = 0; tt < 8; ++tt) {
#pragma unroll
      for (int r = 0; r < 4; ++r) {
        l4[tt][r] = __expf(l4[tt][r] - mx);
        ps += l4[tt][r];
      }
    }
    ps += __shfl_xor(ps, 16, 64);
    ps += __shfl_xor(ps, 32, 64);
    if (lane < 16) redse[wv * 16 + lane] = ps;
    __syncthreads();   // sync2: den ready
    float den = redse[nl];
#pragma unroll
    for (int w = 1; w < 8; ++w) den += redse[w * 16 + nl];
    const float rs = 1.f / den;

    // accumulate P_j/den into Plds (thread-owned cells, fp16 RMW)
#pragma unroll
    for (int tt = 0; tt < 8; ++tt) {
      const int m = wm0 + tt * 16 + g16 * 4;
      unsigned short* pp = &Plds[nl * 1024 + (m ^ (nl * 8))];
      float p0 = l4[tt][0] * rs, p1 = l4[tt][1] * rs;
      float p2 = l4[tt][2] * rs, p3 = l4[tt][3] * rs;
      if (j > 0) {
        const uint2 old = *reinterpret_cast<const uint2*>(pp);
        p0 += h2f((unsigned short)(old.x & 0xffffu));
        p1 += h2f((unsigned short)(old.x >> 16));
        p2 += h2f((unsigned short)(old.y & 0xffffu));
        p3 += h2f((unsigned short)(old.y >> 16));
      }
      uint2 w2; w2.x = pkh(p0, p1); w2.y = pkh(p2, p3);
      *reinterpret_cast<uint2*>(pp) = w2;
    }
  }

  __syncthreads();   // Psum complete

  // Single PV pass: wave covers c-tile ct, m in [mh*512, mh*512+512),
  // explicit 8-deep V load windows.
  const unsigned short* vg = vh + ibo + (size_t)(ct * 16 + nl) * 1024 + mh * 512 + g16 * 8;
  f32x4 oa = f32x4{0.f, 0.f, 0.f, 0.f};
#pragma unroll
  for (int hh = 0; hh < 2; ++hh) {
    uint4 vf[8];
#pragma unroll
    for (int u = 0; u < 8; ++u)
      vf[u] = *reinterpret_cast<const uint4*>(vg + (hh * 8 + u) * 32);
#pragma unroll
    for (int u = 0; u < 8; ++u) {
      const int ml = mh * 512 + (hh * 8 + u) * 32 + g16 * 8;
      const uint4 pf = *reinterpret_cast<const uint4*>(&Plds[nl * 1024 + (ml ^ (nl * 8))]);
      oa = mfmah(bch8(vf[u]), bch8(pf), oa);
    }
  }

  // combine m-halves through LDS, fuse with out_cam
  if (mh == 0) {
#pragma unroll
    for (int r = 0; r < 4; ++r)
      osum[(ct * 16 + g16 * 4 + r) * 16 + nl] = oa[r];
  }
  __syncthreads();
  if (mh == 1) {
    const float* og = ocam + ibo;
    float* outg = tgts + (size_t)(2 * i * 8 + b) * PLANE;
#pragma unroll
    for (int r = 0; r < 4; ++r) {
      const int c = ct * 16 + g16 * 4 + r;
      const int idx = c * N_ + n0 + nl;
      outg[idx] = 0.5f * (oa[r] + osum[c * 16 + nl] + og[idx]);
    }
  }
}

// ---------------------------------------------------------------------------
// alpha[i][j] = 0.5*(softmax_j(mean e_pam) + softmax_j(mean e_cam))
// ---------------------------------------------------------------------------
__global__ void alpha_kernel(const float* __restrict__ esum, float* __restrict__ alpha)
{
  const int t = threadIdx.x;
  if (t >= 9) return;
  const int i = t / 3, j = t % 3;
  float p[3], c[3];
#pragma unroll
  for (int jj = 0; jj < 3; ++jj) {
    p[jj] = esum[i * 3 + jj] * (1.0f / 8388608.0f);
    c[jj] = esum[9 + i * 3 + jj] * (1.0f / 32768.0f);
  }
  const float mp = fmaxf(p[0], fmaxf(p[1], p[2]));
  const float mc = fmaxf(c[0], fmaxf(c[1], c[2]));
  float sp = 0.f, sc = 0.f;
#pragma unroll
  for (int jj = 0; jj < 3; ++jj) { sp += __expf(p[jj] - mp); sc += __expf(c[jj] - mc); }
  alpha[t] = 0.5f * (__expf(p[j] - mp) / sp + __expf(c[j] - mc) / sc);
}

// ---------------------------------------------------------------------------
extern "C" void kernel_launch(void* const* d_in, const int* in_sizes, int n_in,
                              void* d_out, int out_size, void* d_ws, size_t ws_size,
                              hipStream_t stream)
{
  const float* src0 = (const float*)d_in[0];
  const float* src1 = (const float*)d_in[1];
  const float* src2 = (const float*)d_in[2];
  const float* tgt0 = (const float*)d_in[3];
  const float* tgt1 = (const float*)d_in[4];
  const float* tgt2 = (const float*)d_in[5];
  const float* fs0_w = (const float*)d_in[6];  const float* fs0_b = (const float*)d_in[7];
  const float* fs1_w = (const float*)d_in[8];  const float* fs1_b = (const float*)d_in[9];
  const float* fs2_w = (const float*)d_in[10]; const float* fs2_b = (const float*)d_in[11];
  const float* ft0_w = (const float*)d_in[12]; const float* ft0_b = (const float*)d_in[13];
  const float* ft1_w = (const float*)d_in[14]; const float* ft1_b = (const float*)d_in[15];
  const float* ft2_w = (const float*)d_in[16]; const float* ft2_b = (const float*)d_in[17];
  const float* pq_w = (const float*)d_in[18];  const float* pq_b = (const float*)d_in[19];
  const float* pk_w = (const float*)d_in[20];  const float* pk_b = (const float*)d_in[21];
  const float* pv_w = (const float*)d_in[22];  const float* pv_b = (const float*)d_in[23];
  const float* cv_w = (const float*)d_in[24];  const float* cv_b = (const float*)d_in[25];

  float* out = (float*)d_out;
  float* S     = out;                 // srcs region doubles as S storage
  float* alpha = out + SZ;            // 9 floats
  float* tgts  = out + SZ + 9;        // [2L][B][PLANE]

  float* ws   = (float*)d_ws;
  float* T    = ws;
  float* qb   = ws + (size_t)SZ;      // overlay region (fp16 staging)
  float* kb   = ws + (size_t)2 * SZ;  // qT home after proj
  float* vcb  = ws + (size_t)4 * SZ;
  float* ocam = ws + (size_t)5 * SZ;
  float* ecam = ws + (size_t)6 * SZ;                 // 294912
  float* acam = ws + (size_t)6 * SZ + 294912;        // 98304
  float* esum = ws + (size_t)6 * SZ + 393216;        // 18 (pam 9, cam 9)

  // fp16 buffers appended after the fp32 region
  unsigned short* kT = (unsigned short*)(ws + (size_t)6 * SZ + 393216 + 256);
  unsigned short* vh = kT + (size_t)24 * PLANE;
  unsigned short* wh = vh + (size_t)24 * PLANE;      // 98304 ushorts
  unsigned short* w9s = wh + 98304;                  // 73728 ushorts
  unsigned short* w9t = w9s + 73728;
  unsigned short* qT = (unsigned short*)kb;          // dead fp32 slot reused

  // Overlays in qb.. region (each consumed before the next producer writes):
  unsigned short* inTs = (unsigned short*)qb;        // 8*4096*128
  unsigned short* inTt = inTs + 4194304;
  unsigned short* Xs1 = (unsigned short*)qb;         // 8x1024x256
  unsigned short* Xs2 = Xs1 + 2097152;               // 8x1024x512
  unsigned short* Xt1 = Xs1 + 6291456;               // 8x1024x256
  unsigned short* Xt2 = Xs1 + 8388608;               // 8x1024x512

  hipMemsetAsync(esum, 0, 18 * sizeof(float), stream);
  hipMemsetAsync(ecam, 0, 294912 * sizeof(float), stream);

  // conv0 via MFMA: channels-last fp16 inputs + fp16 tap weights
  w9conv_kernel<<<576, 256, 0, stream>>>(fs0_w, ft0_w, w9s, w9t);
  xprep_conv_kernel<<<dim3(16, 2, 64), 256, 0, stream>>>(src0, tgt0, inTs, inTt);
  conv0_mfma_kernel<<<dim3(32, 8, 2), 256, 0, stream>>>(
      inTs, inTt, w9s, w9t, fs0_b, ft0_b, S, T, tgts + (size_t)1 * BPL);

  // fp16 fit GEMMs (single xprep launch overwrites the inT overlay with Xh)
  xprep_fit_kernel<<<dim3(32, 8, 16), 256, 0, stream>>>(
      src1, src2, tgt1, tgt2, Xs1, Xs2, Xt1, Xt2);
  whconv_kernel<<<192, 256, 0, stream>>>(fs1_w, fs2_w, ft1_w, ft2_w, wh);
  gemmh_kernel<<<dim3(16, 16), 256, 0, stream>>>(
      Xs1, Xt1, wh, wh + 49152, fs1_b, ft1_b,
      S + BPL, T + BPL, tgts + (size_t)3 * BPL, 256);
  gemmh_kernel<<<dim3(16, 16), 256, 0, stream>>>(
      Xs2, Xt2, wh + 16384, wh + 65536, fs2_b, ft2_b,
      S + 2 * BPL, T + 2 * BPL, tgts + (size_t)5 * BPL, 512);

  // All 4 projections in one launch, emitting qT/kT/vh fp16 + vcb fp32
  proj_kernel<<<dim3(24, 16, 4), 256, 0, stream>>>(
      T, S, pq_w, pk_w, pv_w, cv_w, pq_b, pk_b, pv_b, cv_b, qT, kT, vh, vcb);

  // CAM (ecam: 288 blocks, atomic partials into zeroed buffer)
  ecam_kernel<<<dim3(72, 4), 256, 0, stream>>>(T, S, ecam, esum + 9);
  acam_kernel<<<24, 256, 0, stream>>>(ecam, acam);
  gemm64_kernel<<<dim3(24, 16), 256, 0, stream>>>(acam, 4096, 1, vcb, PLANE, ocam, PLANE,
                                                  nullptr, 0, 64);

  // PAM + fuse (writes tgts even slots = 0.5*(out_pam + out_cam))
  pam_mfma_kernel<<<1536, 512, 0, stream>>>(qT, kT, vh, ocam, tgts, esum);

  alpha_kernel<<<1, 64, 0, stream>>>(esum, alpha);
}

// Round 16
// 292.065 us; speedup vs baseline: 1.4247x; 1.0161x over previous
//
#include <hip/hip_runtime.h>

// Problem constants
static constexpr int L_ = 3, B_ = 8, C_ = 64, N_ = 1024;
static constexpr int PLANE = C_ * N_;       // 65536
static constexpr int SZ    = L_ * B_ * PLANE; // 1572864
static constexpr int BPL   = B_ * PLANE;    // 524288

#define DI __device__ __forceinline__

typedef _Float16 h8 __attribute__((ext_vector_type(8)));   // 8 fp16 (MFMA A/B frag)
typedef __attribute__((ext_vector_type(4))) float f32x4;   // MFMA C/D frag
typedef unsigned int uint32;

DI float wred_sum(float v) {
#pragma unroll
  for (int m = 1; m < 64; m <<= 1) v += __shfl_xor(v, m, 64);
  return v;
}

DI unsigned short f2h(float f) {
  return __builtin_bit_cast(unsigned short, (_Float16)f);
}
DI float h2f(unsigned short h) {
  return (float)__builtin_bit_cast(_Float16, h);
}
DI uint32 pkh(float a, float b) {
  return (uint32)f2h(a) | ((uint32)f2h(b) << 16);
}
DI h8 bch8(uint4 v) { return __builtin_bit_cast(h8, v); }

DI f32x4 mfmah(h8 a, h8 b, f32x4 c) {
  return __builtin_amdgcn_mfma_f32_16x16x32_f16(a, b, c, 0, 0, 0);
}

// ---------------------------------------------------------------------------
// xprep body: transpose+convert one 64x64 tile of in[K][N] fp32 -> out[N][K]
// fp16. ing/og pre-offset to the (g,kc,nc) tile.
// ---------------------------------------------------------------------------
DI void xprep_body(const float* __restrict__ ing, unsigned short* __restrict__ og,
                   int K, int N, int t, float tl[64][65])
{
#pragma unroll 4
  for (int r = 0; r < 16; ++r) {
    const int kk = r * 4 + (t >> 6);
    tl[kk][t & 63] = ing[(size_t)kk * N + (t & 63)];
  }
  __syncthreads();
  const int mm = t >> 2, kseg = (t & 3) * 16;
  uint32 hw[8];
#pragma unroll
  for (int ii = 0; ii < 8; ++ii)
    hw[ii] = pkh(tl[kseg + 2 * ii][mm], tl[kseg + 2 * ii + 1][mm]);
  unsigned short* o = og + (size_t)mm * K + kseg;
  uint4 h0; h0.x = hw[0]; h0.y = hw[1]; h0.z = hw[2]; h0.w = hw[3];
  uint4 h1; h1.x = hw[4]; h1.y = hw[5]; h1.z = hw[6]; h1.w = hw[7];
  *reinterpret_cast<uint4*>(o)     = h0;
  *reinterpret_cast<uint4*>(o + 8) = h1;
}

// conv inputs: grid (16, 2, 64): x = tsel*8 + g; K=128, N=4096.
__global__ __launch_bounds__(256) void xprep_conv_kernel(
    const float* __restrict__ in_s, const float* __restrict__ in_t,
    unsigned short* __restrict__ o_s, unsigned short* __restrict__ o_t)
{
  __shared__ float tl[64][65];
  const int g = blockIdx.x & 7, ts = blockIdx.x >> 3;
  const int kc = blockIdx.y, nc = blockIdx.z;
  const float* in = ts ? in_t : in_s;
  unsigned short* out = ts ? o_t : o_s;
  const float* ing = in + (size_t)g * 128 * 4096 + (size_t)(kc * 64) * 4096 + nc * 64;
  unsigned short* og = out + ((size_t)g * 4096 + nc * 64) * 128 + kc * 64;
  xprep_body(ing, og, 128, 4096, threadIdx.x, tl);
}

// fit inputs, all 4 tensors in one launch: grid (32, 8, 16): x = ts*8 + g.
// K = 256 for ts 0,2; 512 for ts 1,3. Uniform early-exit when kc >= K/64.
__global__ __launch_bounds__(256) void xprep_fit_kernel(
    const float* __restrict__ s1, const float* __restrict__ s2,
    const float* __restrict__ t1, const float* __restrict__ t2,
    unsigned short* __restrict__ x1, unsigned short* __restrict__ x2,
    unsigned short* __restrict__ x3, unsigned short* __restrict__ x4)
{
  __shared__ float tl[64][65];
  const int g = blockIdx.x & 7, ts = blockIdx.x >> 3;
  const int K = (ts & 1) ? 512 : 256;
  const int kc = blockIdx.y, nc = blockIdx.z;
  if (kc >= (K >> 6)) return;
  const float* in = (ts == 0) ? s1 : (ts == 1) ? s2 : (ts == 2) ? t1 : t2;
  unsigned short* out = (ts == 0) ? x1 : (ts == 1) ? x2 : (ts == 2) ? x3 : x4;
  const float* ing = in + (size_t)g * K * 1024 + (size_t)(kc * 64) * 1024 + nc * 64;
  unsigned short* og = out + ((size_t)g * 1024 + nc * 64) * K + kc * 64;
  xprep_body(ing, og, K, 1024, threadIdx.x, tl);
}

// ---------------------------------------------------------------------------
// wprep: conv weights w[co][ci][k9] -> w9[k9][co][ci] fp16 (both s,t) PLUS
// the 4 fit-GEMM weight conversions (wh1s@0, wh2s@16384, wh1t@49152,
// wh2t@65536). grid 768 = 576 (w9) + 192 (wh).
// ---------------------------------------------------------------------------
__global__ __launch_bounds__(256) void wprep_kernel(
    const float* __restrict__ w_s, const float* __restrict__ w_t,
    unsigned short* __restrict__ w9_s, unsigned short* __restrict__ w9_t,
    const float* __restrict__ w1s, const float* __restrict__ w2s,
    const float* __restrict__ w1t, const float* __restrict__ w2t,
    unsigned short* __restrict__ wh)
{
  const int e = blockIdx.x * 256 + threadIdx.x;
  if (e < 147456) {
    const float* w = (e < 73728) ? w_s : w_t;
    unsigned short* o = (e < 73728) ? w9_s : w9_t;
    const int le = (e < 73728) ? e : e - 73728;
    const int ci = le & 127;
    const int q = le >> 7;
    const int co = q & 63;
    const int k9 = q >> 6;
    o[le] = f2h(w[(co * 128 + ci) * 9 + k9]);
  } else {
    const int p = e - 147456;  // pair index 0..49151
    const float* in; int local; unsigned short* out;
    if (p < 8192)       { in = w1s; local = p;         out = wh; }
    else if (p < 24576) { in = w2s; local = p - 8192;  out = wh + 16384; }
    else if (p < 32768) { in = w1t; local = p - 24576; out = wh + 49152; }
    else                { in = w2t; local = p - 32768; out = wh + 65536; }
    const float2 v = *reinterpret_cast<const float2*>(in + 2 * local);
    *reinterpret_cast<uint32*>(out + 2 * local) = pkh(v.x, v.y);
  }
}

// ---------------------------------------------------------------------------
// conv0 via MFMA: 3x3 s2 p1, 128->64, channels-last fp16 inT[b][pix][ci],
// w9[tap][co][ci]. grid (32 out-rows, 8 b, 2 st), 256 thr = 4 waves.
// ---------------------------------------------------------------------------
__global__ __launch_bounds__(256) void conv0_mfma_kernel(
    const unsigned short* __restrict__ inT_s, const unsigned short* __restrict__ inT_t,
    const unsigned short* __restrict__ w9_s, const unsigned short* __restrict__ w9_t,
    const float* __restrict__ b_s, const float* __restrict__ b_t,
    float* __restrict__ Sout, float* __restrict__ Tout, float* __restrict__ tdup)
{
  const int yr = blockIdx.x;          // output row 0..31
  const int b  = blockIdx.y;
  const int st = blockIdx.z;
  const unsigned short* inT = st ? inT_t : inT_s;
  const unsigned short* w9  = st ? w9_t  : w9_s;
  const float* bias = st ? b_t : b_s;
  float* outA = st ? Tout : Sout;

  const int t = threadIdx.x, lane = t & 63;
  const int ct = t >> 6;              // co-tile
  const int nl = lane & 15, g16 = lane >> 4;
  const unsigned short* inb = inT + (size_t)b * (4096 * 128);
  const unsigned short* wbase = w9 + (size_t)(ct * 16 + nl) * 128;

  f32x4 acc0 = f32x4{0.f, 0.f, 0.f, 0.f};
  f32x4 acc1 = f32x4{0.f, 0.f, 0.f, 0.f};
  const uint4 zz = uint4{0u, 0u, 0u, 0u};

#pragma unroll 1
  for (int tap = 0; tap < 9; ++tap) {
    const int ky = tap / 3, kx = tap - 3 * (tap / 3);
    const int py = 2 * yr - 1 + ky;                 // [-1, 63]
    const int px0 = 2 * nl - 1 + kx;                // nt=0: x = nl
    const int px1 = px0 + 32;                       // nt=1: x = 16+nl (>=31)
    const bool v0 = (py >= 0) && (px0 >= 0);
    const bool v1 = (py >= 0);
    const unsigned short* prow = inb + (ptrdiff_t)py * (64 * 128);
#pragma unroll
    for (int ks = 0; ks < 4; ++ks) {
      const h8 a = bch8(*reinterpret_cast<const uint4*>(
          wbase + tap * 8192 + ks * 32 + g16 * 8));
      const uint4 bv0 = v0 ? *reinterpret_cast<const uint4*>(
                                 prow + px0 * 128 + ks * 32 + g16 * 8) : zz;
      const uint4 bv1 = v1 ? *reinterpret_cast<const uint4*>(
                                 prow + px1 * 128 + ks * 32 + g16 * 8) : zz;
      acc0 = mfmah(a, bch8(bv0), acc0);
      acc1 = mfmah(a, bch8(bv1), acc1);
    }
  }

  const int yb = yr * 32;
#pragma unroll
  for (int r = 0; r < 4; ++r) {
    const int co = ct * 16 + g16 * 4 + r;
    const float bv = bias[co];
    const int idx = (b * 64 + co) * 1024 + yb + nl;
    const float o0 = acc0[r] + bv;
    const float o1 = acc1[r] + bv;
    outA[idx] = o0; outA[idx + 16] = o1;
    if (st) { tdup[idx] = o0; tdup[idx + 16] = o1; }
  }
}

// ---------------------------------------------------------------------------
// Generic fp32 out[g][64][1024] = W[g/wdiv][64][K] @ X[g][K][1024] + bias
// (kept for attn_cam @ vc)
// ---------------------------------------------------------------------------
__global__ __launch_bounds__(256) void gemm64_kernel(
    const float* __restrict__ W, int wstride, int wdiv,
    const float* __restrict__ X, int xstride,
    float* __restrict__ out, int ostride,
    const float* __restrict__ bias, int bstride,
    int K)
{
  const int g  = blockIdx.x;
  const int n0 = blockIdx.y * 64;
  const float* Wg = W + (size_t)(g / wdiv) * wstride;
  const float* Xg = X + (size_t)g * xstride;
  const int t = threadIdx.x;
  __shared__ float Xs[32][64];
  __shared__ float Ws[32][64];
  const int tn = t & 15, cgp = t >> 4;
  const int n4 = tn * 4, co4 = cgp * 4;
  float acc[4][4] = {};

  for (int k0 = 0; k0 < K; k0 += 32) {
    {
      const int kk = t >> 4;
      const int nn = (t & 15) * 4;
      *reinterpret_cast<float4*>(&Xs[kk][nn]) =
          *reinterpret_cast<const float4*>(Xg + (size_t)(k0 + kk) * N_ + n0 + nn);
      *reinterpret_cast<float4*>(&Xs[kk + 16][nn]) =
          *reinterpret_cast<const float4*>(Xg + (size_t)(k0 + kk + 16) * N_ + n0 + nn);
    }
    {
      const int co = t & 63, q4 = t >> 6;
      const float* wp = Wg + (size_t)co * K + k0 + q4 * 8;
      const float4 a = *reinterpret_cast<const float4*>(wp);
      const float4 c = *reinterpret_cast<const float4*>(wp + 4);
      const int kb = q4 * 8;
      Ws[kb + 0][co] = a.x; Ws[kb + 1][co] = a.y; Ws[kb + 2][co] = a.z; Ws[kb + 3][co] = a.w;
      Ws[kb + 4][co] = c.x; Ws[kb + 5][co] = c.y; Ws[kb + 6][co] = c.z; Ws[kb + 7][co] = c.w;
    }
    __syncthreads();
#pragma unroll
    for (int kk = 0; kk < 32; ++kk) {
      const float4 xv = *reinterpret_cast<const float4*>(&Xs[kk][n4]);
      const float4 wv = *reinterpret_cast<const float4*>(&Ws[kk][co4]);
      const float xa[4] = {xv.x, xv.y, xv.z, xv.w};
      const float wa[4] = {wv.x, wv.y, wv.z, wv.w};
#pragma unroll
      for (int a = 0; a < 4; ++a)
#pragma unroll
        for (int b2 = 0; b2 < 4; ++b2)
          acc[a][b2] = fmaf(wa[a], xa[b2], acc[a][b2]);
    }
    __syncthreads();
  }

  float bv[4] = {0.f, 0.f, 0.f, 0.f};
  if (bias) {
    const float* bg = bias + (size_t)(g / wdiv) * bstride;
    bv[0] = bg[co4]; bv[1] = bg[co4 + 1]; bv[2] = bg[co4 + 2]; bv[3] = bg[co4 + 3];
  }
#pragma unroll
  for (int ii = 0; ii < 4; ++ii) {
    float4 o4;
    o4.x = acc[ii][0] + bv[ii]; o4.y = acc[ii][1] + bv[ii];
    o4.z = acc[ii][2] + bv[ii]; o4.w = acc[ii][3] + bv[ii];
    *reinterpret_cast<float4*>(out + (size_t)g * ostride + (co4 + ii) * N_ + n0 + n4) = o4;
  }
}

// ---------------------------------------------------------------------------
// proj: all 4 projections in ONE launch, emitting pam-ready fp16 directly.
// grid (24, 16, 4).
// ---------------------------------------------------------------------------
__global__ __launch_bounds__(256) void proj_kernel(
    const float* __restrict__ Tm, const float* __restrict__ Sm,
    const float* __restrict__ wq, const float* __restrict__ wk,
    const float* __restrict__ wv2, const float* __restrict__ wc,
    const float* __restrict__ bq, const float* __restrict__ bk,
    const float* __restrict__ bv2, const float* __restrict__ bc,
    unsigned short* __restrict__ qT, unsigned short* __restrict__ kT,
    unsigned short* __restrict__ vh, float* __restrict__ vcb)
{
  const int g  = blockIdx.x;          // i*8+b
  const int n0 = blockIdx.y * 64;
  const int z  = blockIdx.z;          // 0=q 1=k 2=v 3=vc
  const float* W  = (z == 0) ? wq : (z == 1) ? wk : (z == 2) ? wv2 : wc;
  const float* bi = (z == 0) ? bq : (z == 1) ? bk : (z == 2) ? bv2 : bc;
  const float* Xg = ((z == 1) ? Sm : Tm) + (size_t)g * PLANE;
  const float* Wg = W + (g >> 3) * 4096;
  const float* bg = bi + (g >> 3) * 64;

  const int t = threadIdx.x;
  __shared__ float Xs[32][64];
  __shared__ float Ws[32][64];
  const int tn = t & 15, cgp = t >> 4;
  const int n4 = tn * 4, co4 = cgp * 4;
  float acc[4][4] = {};

#pragma unroll 1
  for (int k0 = 0; k0 < 64; k0 += 32) {
    {
      const int kk = t >> 4;
      const int nn = (t & 15) * 4;
      *reinterpret_cast<float4*>(&Xs[kk][nn]) =
          *reinterpret_cast<const float4*>(Xg + (size_t)(k0 + kk) * N_ + n0 + nn);
      *reinterpret_cast<float4*>(&Xs[kk + 16][nn]) =
          *reinterpret_cast<const float4*>(Xg + (size_t)(k0 + kk + 16) * N_ + n0 + nn);
    }
    {
      const int co = t & 63, q4 = t >> 6;
      const float* wp = Wg + (size_t)co * 64 + k0 + q4 * 8;
      const float4 a = *reinterpret_cast<const float4*>(wp);
      const float4 c = *reinterpret_cast<const float4*>(wp + 4);
      const int kb = q4 * 8;
      Ws[kb + 0][co] = a.x; Ws[kb + 1][co] = a.y; Ws[kb + 2][co] = a.z; Ws[kb + 3][co] = a.w;
      Ws[kb + 4][co] = c.x; Ws[kb + 5][co] = c.y; Ws[kb + 6][co] = c.z; Ws[kb + 7][co] = c.w;
    }
    __syncthreads();
#pragma unroll
    for (int kk = 0; kk < 32; ++kk) {
      const float4 xv = *reinterpret_cast<const float4*>(&Xs[kk][n4]);
      const float4 wv = *reinterpret_cast<const float4*>(&Ws[kk][co4]);
      const float xa[4] = {xv.x, xv.y, xv.z, xv.w};
      const float wa[4] = {wv.x, wv.y, wv.z, wv.w};
#pragma unroll
      for (int a = 0; a < 4; ++a)
#pragma unroll
        for (int b2 = 0; b2 < 4; ++b2)
          acc[a][b2] = fmaf(wa[a], xa[b2], acc[a][b2]);
    }
    __syncthreads();
  }

  float bvv[4];
#pragma unroll
  for (int ii = 0; ii < 4; ++ii) bvv[ii] = bg[co4 + ii];

  if (z <= 1) {
    unsigned short* out = (z == 0 ? qT : kT);
#pragma unroll
    for (int jj = 0; jj < 4; ++jj) {
      const size_t base = ((size_t)g * 1024 + n0 + n4 + jj) * 64 + co4;
      uint2 w2;
      w2.x = pkh(acc[0][jj] + bvv[0], acc[1][jj] + bvv[1]);
      w2.y = pkh(acc[2][jj] + bvv[2], acc[3][jj] + bvv[3]);
      *reinterpret_cast<uint2*>(out + base) = w2;
    }
  } else if (z == 2) {
#pragma unroll
    for (int ii = 0; ii < 4; ++ii) {
      const size_t base = ((size_t)g * 64 + co4 + ii) * 1024 + n0 + n4;
      uint2 w2;
      w2.x = pkh(acc[ii][0] + bvv[ii], acc[ii][1] + bvv[ii]);
      w2.y = pkh(acc[ii][2] + bvv[ii], acc[ii][3] + bvv[ii]);
      *reinterpret_cast<uint2*>(vh + base) = w2;
    }
  } else {
    float* out = vcb + (size_t)g * PLANE;
#pragma unroll
    for (int ii = 0; ii < 4; ++ii) {
      float4 o4;
      o4.x = acc[ii][0] + bvv[ii]; o4.y = acc[ii][1] + bvv[ii];
      o4.z = acc[ii][2] + bvv[ii]; o4.w = acc[ii][3] + bvv[ii];
      *reinterpret_cast<float4*>(out + (co4 + ii) * N_ + n0 + n4) = o4;
    }
  }
}

// ---------------------------------------------------------------------------
// gemmh: fp16 MFMA fit-GEMM, BOTH K variants in one launch.
// grid (32, 16): x<16 -> K=256 (src1/tgt1), x>=16 -> K=512 (src2/tgt2).
// Within each 16: g<8 = src, g>=8 = tgt (+dual write).
// ---------------------------------------------------------------------------
__global__ __launch_bounds__(256) void gemmh_kernel(
    const unsigned short* __restrict__ X1s, const unsigned short* __restrict__ X1t,
    const unsigned short* __restrict__ X2s, const unsigned short* __restrict__ X2t,
    const unsigned short* __restrict__ wh,
    const float* __restrict__ b1s, const float* __restrict__ b1t,
    const float* __restrict__ b2s, const float* __restrict__ b2t,
    float* __restrict__ S, float* __restrict__ T,
    float* __restrict__ tdup3, float* __restrict__ tdup5)
{
  const int gx = blockIdx.x;
  const bool k5 = gx >= 16;
  const int g = gx & 15;
  const bool isb = g >= 8;
  const int gl = g & 7;
  const int K = k5 ? 512 : 256;
  const unsigned short* X = (k5 ? (isb ? X2t : X2s) : (isb ? X1t : X1s))
                            + (size_t)gl * 1024 * K;
  const unsigned short* W = wh + (k5 ? (isb ? 65536 : 16384) : (isb ? 49152 : 0));
  const float* bias = k5 ? (isb ? b2t : b2s) : (isb ? b1t : b1s);
  float* out = (k5 ? (isb ? T + 2 * BPL : S + 2 * BPL) : (isb ? T + BPL : S + BPL))
               + (size_t)gl * PLANE;
  float* out2 = isb ? (k5 ? tdup5 : tdup3) + (size_t)gl * PLANE : nullptr;

  const int t = threadIdx.x, lane = t & 63, wv = t >> 6;
  const int nl = lane & 15, g16 = lane >> 4;
  const int n0w = blockIdx.y * 64 + wv * 16;

  const unsigned short* xp = X + (size_t)(n0w + nl) * K + g16 * 8;
  const unsigned short* wp = W + (size_t)nl * K + g16 * 8;

  f32x4 acc[4];
#pragma unroll
  for (int ct = 0; ct < 4; ++ct) acc[ct] = f32x4{0.f, 0.f, 0.f, 0.f};

#pragma unroll 4
  for (int kk = 0; kk < K; kk += 32) {
    const h8 a = bch8(*reinterpret_cast<const uint4*>(xp + kk));
#pragma unroll
    for (int ct = 0; ct < 4; ++ct) {
      const h8 bfr = bch8(*reinterpret_cast<const uint4*>(wp + (size_t)ct * 16 * K + kk));
      acc[ct] = mfmah(a, bfr, acc[ct]);
    }
  }

#pragma unroll
  for (int ct = 0; ct < 4; ++ct) {
    const int co = ct * 16 + nl;
    const float bv = bias[co];
    float4 o4;
    o4.x = acc[ct][0] + bv; o4.y = acc[ct][1] + bv;
    o4.z = acc[ct][2] + bv; o4.w = acc[ct][3] + bv;
    const int idx = co * N_ + n0w + g16 * 4;
    *reinterpret_cast<float4*>(out + idx) = o4;
    if (out2) {
      out2[idx] = o4.x; out2[idx + 1] = o4.y;
      out2[idx + 2] = o4.z; out2[idx + 3] = o4.w;
    }
  }
}

// ---------------------------------------------------------------------------
// e_cam partials: grid (72, 4) - each block covers 256 n, atomicAdd into ecam
// (zeroed by memset).
// ---------------------------------------------------------------------------
__global__ __launch_bounds__(256) void ecam_kernel(
    const float* __restrict__ T, const float* __restrict__ S,
    float* __restrict__ ecam, float* __restrict__ esum_cam)
{
  const int bx = blockIdx.x;
  const int b = bx & 7;
  const int j = (bx >> 3) % 3;
  const int i = bx / 24;
  const int ych = blockIdx.y;
  const float* Tg = T + (size_t)(i * 8 + b) * PLANE;
  const float* Sg = S + (size_t)(j * 8 + b) * PLANE;
  const int t = threadIdx.x;
  __shared__ float Ts[64 * 68];
  __shared__ float Ss[64 * 68];
  __shared__ float rs[4];
  float acc[4][4] = {};
  const int c0 = (t & 15) * 4, d0 = (t >> 4) * 4;

  for (int nb = ych * 256; nb < ych * 256 + 256; nb += 64) {
    __syncthreads();
    {
      const int nn = t & 63, rb = t >> 6;
#pragma unroll
      for (int r = 0; r < 16; ++r) {
        const int row = rb * 16 + r;
        Ts[nn * 68 + row] = Tg[row * N_ + nb + nn];
        Ss[nn * 68 + row] = Sg[row * N_ + nb + nn];
      }
    }
    __syncthreads();
#pragma unroll 8
    for (int nn = 0; nn < 64; ++nn) {
      const float4 tv = *reinterpret_cast<const float4*>(&Ts[nn * 68 + c0]);
      const float4 sv = *reinterpret_cast<const float4*>(&Ss[nn * 68 + d0]);
      const float ta[4] = {tv.x, tv.y, tv.z, tv.w};
      const float sa[4] = {sv.x, sv.y, sv.z, sv.w};
#pragma unroll
      for (int ci = 0; ci < 4; ++ci)
#pragma unroll
        for (int di = 0; di < 4; ++di)
          acc[ci][di] = fmaf(ta[ci], sa[di], acc[ci][di]);
    }
  }
  float s = 0.f;
#pragma unroll
  for (int ci = 0; ci < 4; ++ci)
#pragma unroll
    for (int di = 0; di < 4; ++di) s += acc[ci][di];
  s = wred_sum(s);
  if ((t & 63) == 0) rs[t >> 6] = s;
  __syncthreads();
  if (t == 0) atomicAdd(esum_cam + i * 3 + j, rs[0] + rs[1] + rs[2] + rs[3]);

  float* eo = ecam + (size_t)((i * 3 + j) * 8 + b) * 4096;
#pragma unroll
  for (int ci = 0; ci < 4; ++ci)
#pragma unroll
    for (int di = 0; di < 4; ++di)
      atomicAdd(eo + (c0 + ci) * 64 + d0 + di, acc[ci][di]);
}

// ---------------------------------------------------------------------------
// attn_cam[i,b][c][d] = sum_j softmax_d(e_cam[i,j,b,c,:])[d]     grid 24
// ---------------------------------------------------------------------------
__global__ __launch_bounds__(256) void acam_kernel(
    const float* __restrict__ ecam, float* __restrict__ acam)
{
  const int bx = blockIdx.x;
  const int b = bx & 7, i = bx >> 3;
  const int t = threadIdx.x;
  const int c = t >> 2, seg = t & 3;
  float acc[16] = {};
#pragma unroll
  for (int j = 0; j < 3; ++j) {
    const float* e = ecam + (size_t)((i * 3 + j) * 8 + b) * 4096 + c * 64 + seg * 16;
    float ev[16];
#pragma unroll
    for (int r = 0; r < 4; ++r) {
      const float4 v4 = *reinterpret_cast<const float4*>(e + r * 4);
      ev[4 * r] = v4.x; ev[4 * r + 1] = v4.y; ev[4 * r + 2] = v4.z; ev[4 * r + 3] = v4.w;
    }
    float mx = ev[0];
#pragma unroll
    for (int r = 1; r < 16; ++r) mx = fmaxf(mx, ev[r]);
    mx = fmaxf(mx, __shfl_xor(mx, 1, 4));
    mx = fmaxf(mx, __shfl_xor(mx, 2, 4));
    float pv[16], ss = 0.f;
#pragma unroll
    for (int r = 0; r < 16; ++r) { pv[r] = __expf(ev[r] - mx); ss += pv[r]; }
    ss += __shfl_xor(ss, 1, 4);
    ss += __shfl_xor(ss, 2, 4);
    const float rc = 1.f / ss;
#pragma unroll
    for (int r = 0; r < 16; ++r) acc[r] += pv[r] * rc;
  }
  float* ao = acam + (size_t)(i * 8 + b) * 4096 + c * 64 + seg * 16;
#pragma unroll
  for (int r = 0; r < 4; ++r) {
    float4 o4; o4.x = acc[4 * r]; o4.y = acc[4 * r + 1]; o4.z = acc[4 * r + 2]; o4.w = acc[4 * r + 3];
    *reinterpret_cast<float4*>(ao + r * 4) = o4;
  }
}

// ---------------------------------------------------------------------------
// PAM via fp16 MFMA, 8 waves x 128 m, Psum in LDS across j, single PV pass.
// SINGLE barrier per j: each wave exp's vs its OWN max (l-mx_w <= 0, safe)
// and publishes {wave max, wave den, raw sum} BEFORE the barrier; block max
// and den = sum_w den_w*exp(mx_w-mx) are folded into the P-write scale.
// Red-buffers double-buffered by j parity (j and j+2 separated by 2 barriers).
// grid 1536 = (i, b, qt), 512 threads. 5 barriers total (was 7).
// ---------------------------------------------------------------------------
__global__ __launch_bounds__(512, 4) void pam_mfma_kernel(
    const unsigned short* __restrict__ qT, const unsigned short* __restrict__ kT,
    const unsigned short* __restrict__ vh,
    const float* __restrict__ ocam, float* __restrict__ tgts, float* __restrict__ esum_pam)
{
  const int bx = blockIdx.x;
  const int qt = bx & 63;
  const int b  = (bx >> 6) & 7;
  const int i  = bx >> 9;
  const int n0 = qt * 16;
  const int t = threadIdx.x;
  const int lane = t & 63;
  const int wv = t >> 6;             // 0..7
  const int nl = lane & 15;
  const int g16 = lane >> 4;

  __shared__ unsigned short Plds[16 * 1024];  // 32 KB fp16 Psum, [n][m ^ (8n)]
  __shared__ float osum[64 * 16];             // 4 KB m-half combine
  __shared__ float redmx[2][128];             // j-parity double buffered
  __shared__ float redse[2][128];
  __shared__ float redes[2][8];

  const size_t ibo = (size_t)(i * 8 + b) * PLANE;
  const size_t gbase = (size_t)(i * 8 + b) * 1024;

  // Q B-fragments: direct contiguous fp16 loads from qT[g][n][c]
  const unsigned short* qp = qT + (gbase + n0 + nl) * 64 + g16 * 8;
  const h8 qh0 = bch8(*reinterpret_cast<const uint4*>(qp));
  const h8 qh1 = bch8(*reinterpret_cast<const uint4*>(qp + 32));

  const int wm0 = wv * 128;
  const int ct = wv & 3;
  const int mh = wv >> 2;

#pragma unroll 1
  for (int j = 0; j < 3; ++j) {
    const int pj = j & 1;
    const unsigned short* kp =
        kT + ((size_t)(j * 8 + b) * 1024 + wm0 + nl) * 64 + g16 * 8;

    // QK: two half-passes, each with an explicit 8-deep load window
    f32x4 l4[8];
#pragma unroll
    for (int hh = 0; hh < 2; ++hh) {
      uint4 kf[8];
#pragma unroll
      for (int tt = 0; tt < 4; ++tt) {
        const int off = (hh * 4 + tt) * 1024;
        kf[2 * tt]     = *reinterpret_cast<const uint4*>(kp + off);
        kf[2 * tt + 1] = *reinterpret_cast<const uint4*>(kp + off + 32);
      }
#pragma unroll
      for (int tt = 0; tt < 4; ++tt) {
        f32x4 a = f32x4{0.f, 0.f, 0.f, 0.f};
        a = mfmah(bch8(kf[2 * tt]), qh0, a);
        a = mfmah(bch8(kf[2 * tt + 1]), qh1, a);
        l4[hh * 4 + tt] = a;
      }
    }

    // per-(wave,nl) max over the wave's 128 m + raw logit sum (wave)
    float pm = -3.4e38f, es = 0.f;
#pragma unroll
    for (int tt = 0; tt < 8; ++tt) {
#pragma unroll
      for (int r = 0; r < 4; ++r) { pm = fmaxf(pm, l4[tt][r]); es += l4[tt][r]; }
    }
    pm = fmaxf(pm, __shfl_xor(pm, 16, 64));
    pm = fmaxf(pm, __shfl_xor(pm, 32, 64));
    es = wred_sum(es);

    // exp vs OWN wave max (l - pm <= 0: no overflow), per-wave den
    float ps = 0.f;
#pragma unroll
    for (int tt = 0; tt < 8; ++tt) {
#pragma unroll
      for (int r = 0; r < 4; ++r) {
        l4[tt][r] = __expf(l4[tt][r] - pm);
        ps += l4[tt][r];
      }
    }
    ps += __shfl_xor(ps, 16, 64);
    ps += __shfl_xor(ps, 32, 64);

    if (lane < 16) { redmx[pj][wv * 16 + lane] = pm; redse[pj][wv * 16 + lane] = ps; }
    if (lane == 0) redes[pj][wv] = es;
    __syncthreads();   // the ONLY barrier for this j

    // block max + rescaled den
    float mx = redmx[pj][nl];
#pragma unroll
    for (int w = 1; w < 8; ++w) mx = fmaxf(mx, redmx[pj][w * 16 + nl]);
    float den = 0.f;
#pragma unroll
    for (int w = 0; w < 8; ++w)
      den += redse[pj][w * 16 + nl] * __expf(redmx[pj][w * 16 + nl] - mx);
    const float sc = __expf(pm - mx) / den;

    if (t == 0) {
      float s = 0.f;
#pragma unroll
      for (int w = 0; w < 8; ++w) s += redes[pj][w];
      atomicAdd(esum_pam + i * 3 + j, s);
    }

    // accumulate P_j (scaled) into Plds (thread-owned cells, fp16 RMW)
#pragma unroll
    for (int tt = 0; tt < 8; ++tt) {
      const int m = wm0 + tt * 16 + g16 * 4;
      unsigned short* pp = &Plds[nl * 1024 + (m ^ (nl * 8))];
      float p0 = l4[tt][0] * sc, p1 = l4[tt][1] * sc;
      float p2 = l4[tt][2] * sc, p3 = l4[tt][3] * sc;
      if (j > 0) {
        const uint2 old = *reinterpret_cast<const uint2*>(pp);
        p0 += h2f((unsigned short)(old.x & 0xffffu));
        p1 += h2f((unsigned short)(old.x >> 16));
        p2 += h2f((unsigned short)(old.y & 0xffffu));
        p3 += h2f((unsigned short)(old.y >> 16));
      }
      uint2 w2; w2.x = pkh(p0, p1); w2.y = pkh(p2, p3);
      *reinterpret_cast<uint2*>(pp) = w2;
    }
  }

  __syncthreads();   // Psum complete

  // Single PV pass: wave covers c-tile ct, m in [mh*512, mh*512+512),
  // explicit 8-deep V load windows.
  const unsigned short* vg = vh + ibo + (size_t)(ct * 16 + nl) * 1024 + mh * 512 + g16 * 8;
  f32x4 oa = f32x4{0.f, 0.f, 0.f, 0.f};
#pragma unroll
  for (int hh = 0; hh < 2; ++hh) {
    uint4 vf[8];
#pragma unroll
    for (int u = 0; u < 8; ++u)
      vf[u] = *reinterpret_cast<const uint4*>(vg + (hh * 8 + u) * 32);
#pragma unroll
    for (int u = 0; u < 8; ++u) {
      const int ml = mh * 512 + (hh * 8 + u) * 32 + g16 * 8;
      const uint4 pf = *reinterpret_cast<const uint4*>(&Plds[nl * 1024 + (ml ^ (nl * 8))]);
      oa = mfmah(bch8(vf[u]), bch8(pf), oa);
    }
  }

  // combine m-halves through LDS, fuse with out_cam
  if (mh == 0) {
#pragma unroll
    for (int r = 0; r < 4; ++r)
      osum[(ct * 16 + g16 * 4 + r) * 16 + nl] = oa[r];
  }
  __syncthreads();
  if (mh == 1) {
    const float* og = ocam + ibo;
    float* outg = tgts + (size_t)(2 * i * 8 + b) * PLANE;
#pragma unroll
    for (int r = 0; r < 4; ++r) {
      const int c = ct * 16 + g16 * 4 + r;
      const int idx = c * N_ + n0 + nl;
      outg[idx] = 0.5f * (oa[r] + osum[c * 16 + nl] + og[idx]);
    }
  }
}

// ---------------------------------------------------------------------------
// alpha[i][j] = 0.5*(softmax_j(mean e_pam) + softmax_j(mean e_cam))
// ---------------------------------------------------------------------------
__global__ void alpha_kernel(const float* __restrict__ esum, float* __restrict__ alpha)
{
  const int t = threadIdx.x;
  if (t >= 9) return;
  const int i = t / 3, j = t % 3;
  float p[3], c[3];
#pragma unroll
  for (int jj = 0; jj < 3; ++jj) {
    p[jj] = esum[i * 3 + jj] * (1.0f / 8388608.0f);
    c[jj] = esum[9 + i * 3 + jj] * (1.0f / 32768.0f);
  }
  const float mp = fmaxf(p[0], fmaxf(p[1], p[2]));
  const float mc = fmaxf(c[0], fmaxf(c[1], c[2]));
  float sp = 0.f, sc = 0.f;
#pragma unroll
  for (int jj = 0; jj < 3; ++jj) { sp += __expf(p[jj] - mp); sc += __expf(c[jj] - mc); }
  alpha[t] = 0.5f * (__expf(p[j] - mp) / sp + __expf(c[j] - mc) / sc);
}

// ---------------------------------------------------------------------------
extern "C" void kernel_launch(void* const* d_in, const int* in_sizes, int n_in,
                              void* d_out, int out_size, void* d_ws, size_t ws_size,
                              hipStream_t stream)
{
  const float* src0 = (const float*)d_in[0];
  const float* src1 = (const float*)d_in[1];
  const float* src2 = (const float*)d_in[2];
  const float* tgt0 = (const float*)d_in[3];
  const float* tgt1 = (const float*)d_in[4];
  const float* tgt2 = (const float*)d_in[5];
  const float* fs0_w = (const float*)d_in[6];  const float* fs0_b = (const float*)d_in[7];
  const float* fs1_w = (const float*)d_in[8];  const float* fs1_b = (const float*)d_in[9];
  const float* fs2_w = (const float*)d_in[10]; const float* fs2_b = (const float*)d_in[11];
  const float* ft0_w = (const float*)d_in[12]; const float* ft0_b = (const float*)d_in[13];
  const float* ft1_w = (const float*)d_in[14]; const float* ft1_b = (const float*)d_in[15];
  const float* ft2_w = (const float*)d_in[16]; const float* ft2_b = (const float*)d_in[17];
  const float* pq_w = (const float*)d_in[18];  const float* pq_b = (const float*)d_in[19];
  const float* pk_w = (const float*)d_in[20];  const float* pk_b = (const float*)d_in[21];
  const float* pv_w = (const float*)d_in[22];  const float* pv_b = (const float*)d_in[23];
  const float* cv_w = (const float*)d_in[24];  const float* cv_b = (const float*)d_in[25];

  float* out = (float*)d_out;
  float* S     = out;                 // srcs region doubles as S storage
  float* alpha = out + SZ;            // 9 floats
  float* tgts  = out + SZ + 9;        // [2L][B][PLANE]

  float* ws   = (float*)d_ws;
  float* T    = ws;
  float* qb   = ws + (size_t)SZ;      // overlay region (fp16 staging)
  float* kb   = ws + (size_t)2 * SZ;  // qT home after proj
  float* vcb  = ws + (size_t)4 * SZ;
  float* ocam = ws + (size_t)5 * SZ;
  float* ecam = ws + (size_t)6 * SZ;                 // 294912
  float* acam = ws + (size_t)6 * SZ + 294912;        // 98304
  float* esum = ws + (size_t)6 * SZ + 393216;        // 18 (pam 9, cam 9)

  // fp16 buffers appended after the fp32 region
  unsigned short* kT = (unsigned short*)(ws + (size_t)6 * SZ + 393216 + 256);
  unsigned short* vh = kT + (size_t)24 * PLANE;
  unsigned short* wh = vh + (size_t)24 * PLANE;      // 98304 ushorts
  unsigned short* w9s = wh + 98304;                  // 73728 ushorts
  unsigned short* w9t = w9s + 73728;
  unsigned short* qT = (unsigned short*)kb;          // dead fp32 slot reused

  // Overlays in qb.. region (each consumed before the next producer writes):
  unsigned short* inTs = (unsigned short*)qb;        // 8*4096*128
  unsigned short* inTt = inTs + 4194304;
  unsigned short* Xs1 = (unsigned short*)qb;         // 8x1024x256
  unsigned short* Xs2 = Xs1 + 2097152;               // 8x1024x512
  unsigned short* Xt1 = Xs1 + 6291456;               // 8x1024x256
  unsigned short* Xt2 = Xs1 + 8388608;               // 8x1024x512

  hipMemsetAsync(esum, 0, 18 * sizeof(float), stream);
  hipMemsetAsync(ecam, 0, 294912 * sizeof(float), stream);

  // weight conversions (conv taps + fit GEMM weights) in one launch
  wprep_kernel<<<768, 256, 0, stream>>>(fs0_w, ft0_w, w9s, w9t,
                                        fs1_w, fs2_w, ft1_w, ft2_w, wh);

  // conv0 via MFMA: channels-last fp16 inputs + fp16 tap weights
  xprep_conv_kernel<<<dim3(16, 2, 64), 256, 0, stream>>>(src0, tgt0, inTs, inTt);
  conv0_mfma_kernel<<<dim3(32, 8, 2), 256, 0, stream>>>(
      inTs, inTt, w9s, w9t, fs0_b, ft0_b, S, T, tgts + (size_t)1 * BPL);

  // fp16 fit GEMMs (single xprep launch overwrites the inT overlay with Xh)
  xprep_fit_kernel<<<dim3(32, 8, 16), 256, 0, stream>>>(
      src1, src2, tgt1, tgt2, Xs1, Xs2, Xt1, Xt2);
  gemmh_kernel<<<dim3(32, 16), 256, 0, stream>>>(
      Xs1, Xt1, Xs2, Xt2, wh, fs1_b, ft1_b, fs2_b, ft2_b,
      S, T, tgts + (size_t)3 * BPL, tgts + (size_t)5 * BPL);

  // All 4 projections in one launch, emitting qT/kT/vh fp16 + vcb fp32
  proj_kernel<<<dim3(24, 16, 4), 256, 0, stream>>>(
      T, S, pq_w, pk_w, pv_w, cv_w, pq_b, pk_b, pv_b, cv_b, qT, kT, vh, vcb);

  // CAM (ecam: 288 blocks, atomic partials into zeroed buffer)
  ecam_kernel<<<dim3(72, 4), 256, 0, stream>>>(T, S, ecam, esum + 9);
  acam_kernel<<<24, 256, 0, stream>>>(ecam, acam);
  gemm64_kernel<<<dim3(24, 16), 256, 0, stream>>>(acam, 4096, 1, vcb, PLANE, ocam, PLANE,
                                                  nullptr, 0, 64);

  // PAM + fuse (writes tgts even slots = 0.5*(out_pam + out_cam))
  pam_mfma_kernel<<<1536, 512, 0, stream>>>(qT, kT, vh, ocam, tgts, esum);

  alpha_kernel<<<1, 64, 0, stream>>>(esum, alpha);
}